// Round 1
// baseline (4916.673 us; speedup 1.0000x reference)
//
#include <hip/hip_runtime.h>

constexpr int PTS = 2048;   // points per batch
constexpr int KK  = 20;     // knn

static __device__ __forceinline__ float lrelu(float x) { return x >= 0.f ? x : 0.2f * x; }
static __device__ __forceinline__ float rl(float v, int l) {
  return __int_as_float(__builtin_amdgcn_readlane(__float_as_int(v), l));
}
static __device__ __forceinline__ void argmax64(float& v, int& m) {
#pragma unroll
  for (int mask = 1; mask < 64; mask <<= 1) {
    float ov = __shfl_xor(v, mask, 64);
    int om = __shfl_xor(m, mask, 64);
    if (ov > v || (ov == v && om < m)) { v = ov; m = om; }
  }
}

// ---------------- exact kNN (top-20 of 2048), 8 points per block ----------------
// xc layout: [B][C][PTS].  d' = 2*<x_n,x_m> - ||x_m||^2 (rank-equal to ref's d).
template <int C>
__global__ __launch_bounds__(256) void knn_k(const float* __restrict__ xc, int* __restrict__ idxout) {
  constexpr int CP = (C + 3) & ~3;
  constexpr int TROW = 260;        // 256 m + pad
  constexpr int CROW = CP + 4;
  extern __shared__ float lds[];
  float* dist = lds;               // [8][64][33]  (dist[p][m&63][m>>6])
  float* tile = lds + 8 * 2112;    // [CP][TROW]
  float* ctrs = tile + CP * TROW;  // [8][CROW]
  const int tid = threadIdx.x, lane = tid & 63, wid = tid >> 6;
  const int bid = blockIdx.x;
  const int b = bid >> 8;               // 256 blocks per batch
  const int n0 = (bid & 255) << 3;      // 8 points

  for (int q = tid; q < 8 * CP; q += 256) {
    int p = q / CP, c = q % CP;
    ctrs[p * CROW + c] = (c < C) ? xc[((long long)b * C + c) * PTS + n0 + p] : 0.f;
  }
  const int p0 = wid * 2, p1 = p0 + 1;
  for (int t = 0; t < 8; ++t) {
    __syncthreads();
    const int m0 = t << 8;
    for (int q = tid; q < CP * 64; q += 256) {
      int c = q >> 6, m4 = (q & 63) << 2;
      float4 v = {0.f, 0.f, 0.f, 0.f};
      if (c < C) v = *(const float4*)&xc[((long long)b * C + c) * PTS + m0 + m4];
      *(float4*)&tile[c * TROW + m4] = v;
    }
    __syncthreads();
    float a0[4] = {}, a1[4] = {}, axx[4] = {};
#pragma unroll 4
    for (int c = 0; c < CP; c += 4) {
      const float4 q0 = *(const float4*)&ctrs[p0 * CROW + c];
      const float4 q1 = *(const float4*)&ctrs[p1 * CROW + c];
      const float q0a[4] = {q0.x, q0.y, q0.z, q0.w};
      const float q1a[4] = {q1.x, q1.y, q1.z, q1.w};
#pragma unroll
      for (int k = 0; k < 4; ++k) {
        const float4 tv = *(const float4*)&tile[(c + k) * TROW + (lane << 2)];
        const float ta[4] = {tv.x, tv.y, tv.z, tv.w};
#pragma unroll
        for (int j = 0; j < 4; ++j) {
          a0[j] = fmaf(ta[j], q0a[k], a0[j]);
          a1[j] = fmaf(ta[j], q1a[k], a1[j]);
          axx[j] = fmaf(ta[j], ta[j], axx[j]);
        }
      }
    }
#pragma unroll
    for (int j = 0; j < 4; ++j) {
      const int m = m0 + (lane << 2) + j;
      const int s = m & 63, jj = m >> 6;
      dist[p0 * 2112 + s * 33 + jj] = 2.f * a0[j] - axx[j];
      dist[p1 * 2112 + s * 33 + jj] = 2.f * a1[j] - axx[j];
    }
  }
  __syncthreads();
  // selection: each wave handles its 2 points; seg s = lane holds m = s + 64*j
  for (int s2 = 0; s2 < 2; ++s2) {
    const int p = p0 + s2, n = n0 + p;
    float* dp = dist + p * 2112;
    float bv = -3.4e38f; int bm = 1 << 29;
#pragma unroll 4
    for (int j = 0; j < 32; ++j) {
      float v = dp[lane * 33 + j];
      if (v > bv) { bv = v; bm = lane + (j << 6); }   // ascending m: strict > keeps lowest idx
    }
    int keep = 0;
    for (int r = 0; r < KK; ++r) {
      float cv = bv; int cm = bm;
      argmax64(cv, cm);
      if (lane == r) keep = cm;
      const int sm = cm & 63;
      if (lane == 0) dp[sm * 33 + (cm >> 6)] = -3.4e38f;   // persistent invalidation
      asm volatile("s_waitcnt lgkmcnt(0)" ::: "memory");
      const int jj = lane & 31;                            // all-lane rescan of seg sm
      float v2 = dp[sm * 33 + jj];
      int m2 = sm + (jj << 6);
      if (m2 == cm) v2 = -3.4e38f;
      argmax64(v2, m2);
      if (lane == sm) { bv = v2; bm = m2; }
    }
    if (lane < KK) idxout[((long long)b * PTS + n) * KK + lane] = keep;
  }
}

// ---------------- EdgeConv block 1 (C=3 -> 64 -> 64, max over k) ----------------
__global__ __launch_bounds__(64, 2) void edge1_k(
    const float* __restrict__ pts, const int* __restrict__ idxb,
    const float* __restrict__ w1, const float* __restrict__ s1, const float* __restrict__ b1,
    const float* __restrict__ w2, const float* __restrict__ s2, const float* __restrict__ b2,
    float* __restrict__ x1t, float* __restrict__ x1c) {
  const int lane = threadIdx.x;
  const int bid = blockIdx.x;
  const int b = bid >> 7, n0 = (bid & 127) << 4;
  float w1r[6];
#pragma unroll
  for (int k = 0; k < 6; ++k) w1r[k] = w1[lane * 6 + k];
  float w2r[64];
#pragma unroll
  for (int k = 0; k < 16; ++k) {
    const float4 v = *(const float4*)&w2[lane * 64 + 4 * k];
    w2r[4 * k] = v.x; w2r[4 * k + 1] = v.y; w2r[4 * k + 2] = v.z; w2r[4 * k + 3] = v.w;
  }
  const float s1o = s1[lane], b1o = b1[lane], s2o = s2[lane], b2o = b2[lane];
  const float* pb = pts + (long long)b * 3 * PTS;
  for (int pt = 0; pt < 16; ++pt) {
    const int n = n0 + pt;
    const float px = pb[n], py = pb[PTS + n], pz = pb[2 * PTS + n];
    const float cc = w1r[3] * px + w1r[4] * py + w1r[5] * pz;
    float gm = -3.4e38f;
    for (int j = 0; j < KK; ++j) {
      const int m = idxb[((long long)b * PTS + n) * KK + j];
      const float dx = pb[m] - px, dy = pb[PTS + m] - py, dz = pb[2 * PTS + m] - pz;
      const float acc = fmaf(w1r[0], dx, fmaf(w1r[1], dy, fmaf(w1r[2], dz, cc)));
      const float y1 = lrelu(fmaf(s1o, acc, b1o));
      float d0 = 0.f, d1 = 0.f;
#pragma unroll
      for (int c = 0; c < 64; c += 2) {
        d0 = fmaf(w2r[c], rl(y1, c), d0);
        d1 = fmaf(w2r[c + 1], rl(y1, c + 1), d1);
      }
      gm = fmaxf(gm, lrelu(fmaf(s2o, d0 + d1, b2o)));
    }
    x1t[((long long)b * PTS + n) * 64 + lane] = gm;
    x1c[((long long)b * 64 + lane) * PTS + n] = gm;
  }
}

// ---------------- EdgeConv block 2 (C=64 -> 128-in conv -> 64 -> 64, max) ----------------
__global__ __launch_bounds__(64, 2) void edge2_k(
    const float* __restrict__ xt, const int* __restrict__ idxb,
    const float* __restrict__ w3, const float* __restrict__ s3, const float* __restrict__ b3,
    const float* __restrict__ w4, const float* __restrict__ s4, const float* __restrict__ b4,
    float* __restrict__ x2t, float* __restrict__ x2c) {
  const int lane = threadIdx.x;
  const int bid = blockIdx.x;
  const int b = bid >> 7, n0 = (bid & 127) << 4;
  float wa[64], wb[64], w4r[64];
#pragma unroll
  for (int k = 0; k < 16; ++k) {
    float4 v = *(const float4*)&w3[lane * 128 + 4 * k];
    wa[4 * k] = v.x; wa[4 * k + 1] = v.y; wa[4 * k + 2] = v.z; wa[4 * k + 3] = v.w;
    v = *(const float4*)&w3[lane * 128 + 64 + 4 * k];
    wb[4 * k] = v.x; wb[4 * k + 1] = v.y; wb[4 * k + 2] = v.z; wb[4 * k + 3] = v.w;
    v = *(const float4*)&w4[lane * 64 + 4 * k];
    w4r[4 * k] = v.x; w4r[4 * k + 1] = v.y; w4r[4 * k + 2] = v.z; w4r[4 * k + 3] = v.w;
  }
  const float s3o = s3[lane], b3o = b3[lane], s4o = s4[lane], b4o = b4[lane];
  for (int pt = 0; pt < 16; ++pt) {
    const int n = n0 + pt;
    const float ctro = xt[((long long)b * PTS + n) * 64 + lane];
    float c0 = 0.f, c1 = 0.f;
#pragma unroll
    for (int c = 0; c < 64; c += 2) {
      c0 = fmaf(wb[c], rl(ctro, c), c0);
      c1 = fmaf(wb[c + 1], rl(ctro, c + 1), c1);
    }
    const float cc = c0 + c1;
    float gm = -3.4e38f;
    for (int j = 0; j < KK; ++j) {
      const int m = idxb[((long long)b * PTS + n) * KK + j];
      const float df = xt[((long long)b * PTS + m) * 64 + lane] - ctro;
      float a0 = cc, a1 = 0.f;
#pragma unroll
      for (int c = 0; c < 64; c += 2) {
        a0 = fmaf(wa[c], rl(df, c), a0);
        a1 = fmaf(wa[c + 1], rl(df, c + 1), a1);
      }
      const float y1 = lrelu(fmaf(s3o, a0 + a1, b3o));
      float d0 = 0.f, d1 = 0.f;
#pragma unroll
      for (int c = 0; c < 64; c += 2) {
        d0 = fmaf(w4r[c], rl(y1, c), d0);
        d1 = fmaf(w4r[c + 1], rl(y1, c + 1), d1);
      }
      gm = fmaxf(gm, lrelu(fmaf(s4o, d0 + d1, b4o)));
    }
    x2t[((long long)b * PTS + n) * 64 + lane] = gm;
    x2c[((long long)b * 64 + lane) * PTS + n] = gm;
  }
}

// ---------------- EdgeConv block 3 (single conv 128-in -> 64, max) ----------------
__global__ __launch_bounds__(64, 2) void edge3_k(
    const float* __restrict__ xt, const int* __restrict__ idxb,
    const float* __restrict__ w5, const float* __restrict__ s5, const float* __restrict__ b5,
    float* __restrict__ x3c) {
  const int lane = threadIdx.x;
  const int bid = blockIdx.x;
  const int b = bid >> 7, n0 = (bid & 127) << 4;
  float wa[64], wb[64];
#pragma unroll
  for (int k = 0; k < 16; ++k) {
    float4 v = *(const float4*)&w5[lane * 128 + 4 * k];
    wa[4 * k] = v.x; wa[4 * k + 1] = v.y; wa[4 * k + 2] = v.z; wa[4 * k + 3] = v.w;
    v = *(const float4*)&w5[lane * 128 + 64 + 4 * k];
    wb[4 * k] = v.x; wb[4 * k + 1] = v.y; wb[4 * k + 2] = v.z; wb[4 * k + 3] = v.w;
  }
  const float s5o = s5[lane], b5o = b5[lane];
  for (int pt = 0; pt < 16; ++pt) {
    const int n = n0 + pt;
    const float ctro = xt[((long long)b * PTS + n) * 64 + lane];
    float c0 = 0.f, c1 = 0.f;
#pragma unroll
    for (int c = 0; c < 64; c += 2) {
      c0 = fmaf(wb[c], rl(ctro, c), c0);
      c1 = fmaf(wb[c + 1], rl(ctro, c + 1), c1);
    }
    const float cc = c0 + c1;
    float gm = -3.4e38f;
    for (int j = 0; j < KK; ++j) {
      const int m = idxb[((long long)b * PTS + n) * KK + j];
      const float df = xt[((long long)b * PTS + m) * 64 + lane] - ctro;
      float a0 = cc, a1 = 0.f;
#pragma unroll
      for (int c = 0; c < 64; c += 2) {
        a0 = fmaf(wa[c], rl(df, c), a0);
        a1 = fmaf(wa[c + 1], rl(df, c + 1), a1);
      }
      gm = fmaxf(gm, lrelu(fmaf(s5o, a0 + a1, b5o)));
    }
    x3c[((long long)b * 64 + lane) * PTS + n] = gm;
  }
}

// ---------------- generic f32 GEMM: out = affine_lrelu(W[O,C] * X[C,PTS]) ----------------
// MODE 0: store [b][O][PTS] (+optional per-(b,o) pre-bias tadd); MODE 1: max over n -> gpart; MODE 2: store [b][PTS][O]
struct SrcTab { const float* p[4]; long long bs[4]; };

template <int MODE>
__global__ __launch_bounds__(256) void gemm_k(
    const float* __restrict__ W, int wstride, int c0, SrcTab tab, int C,
    const float* __restrict__ sv, const float* __restrict__ bv, const float* __restrict__ tadd,
    float* __restrict__ out, int O) {
  __shared__ float wT[32 * 68];   // [c][o]
  __shared__ float xT[32 * 132];  // [c][n]
  const int tid = threadIdx.x;
  const int nt = blockIdx.x, ot = blockIdx.y, b = blockIdx.z;
  const int n0 = nt * 128, o0 = ot * 64;
  const int og = tid & 15, ng = tid >> 4;
  float acc[4][8] = {};
  for (int cc = 0; cc < C; cc += 32) {
    __syncthreads();
    for (int q = tid; q < 512; q += 256) {
      const int row = q >> 3, c4 = (q & 7) << 2;
      const float4 v = *(const float4*)&W[(long long)(o0 + row) * wstride + c0 + cc + c4];
      wT[(c4 + 0) * 68 + row] = v.x;
      wT[(c4 + 1) * 68 + row] = v.y;
      wT[(c4 + 2) * 68 + row] = v.z;
      wT[(c4 + 3) * 68 + row] = v.w;
    }
    for (int q = tid; q < 1024; q += 256) {
      const int c = q >> 5, n4 = (q & 31) << 2;
      const int cg = cc + c;
      const float4 v = *(const float4*)(tab.p[cg >> 6] + tab.bs[cg >> 6] * b + (long long)(cg & 63) * PTS + n0 + n4);
      *(float4*)&xT[c * 132 + n4] = v;
    }
    __syncthreads();
#pragma unroll 8
    for (int c = 0; c < 32; ++c) {
      const float4 av = *(const float4*)&wT[c * 68 + og * 4];
      const float4 x0 = *(const float4*)&xT[c * 132 + ng * 8];
      const float4 x1 = *(const float4*)&xT[c * 132 + ng * 8 + 4];
      const float aa[4] = {av.x, av.y, av.z, av.w};
      const float xx[8] = {x0.x, x0.y, x0.z, x0.w, x1.x, x1.y, x1.z, x1.w};
#pragma unroll
      for (int oi = 0; oi < 4; ++oi)
#pragma unroll
        for (int nj = 0; nj < 8; ++nj) acc[oi][nj] = fmaf(aa[oi], xx[nj], acc[oi][nj]);
    }
  }
  if (MODE == 1) {
    __syncthreads();
    float* red = xT;
#pragma unroll
    for (int oi = 0; oi < 4; ++oi) {
      const int o = o0 + og * 4 + oi;
      const float s = sv[o], bb = bv[o];
      float pm = -3.4e38f;
#pragma unroll
      for (int nj = 0; nj < 8; ++nj) pm = fmaxf(pm, lrelu(fmaf(s, acc[oi][nj], bb)));
      red[(og * 4 + oi) * 16 + ng] = pm;
    }
    __syncthreads();
    if (tid < 64) {
      float m = red[tid * 16];
#pragma unroll
      for (int k = 1; k < 16; ++k) m = fmaxf(m, red[tid * 16 + k]);
      out[((long long)b * 16 + nt) * 1024 + o0 + tid] = m;
    }
  } else if (MODE == 0) {
#pragma unroll
    for (int oi = 0; oi < 4; ++oi) {
      const int o = o0 + og * 4 + oi;
      const float s = sv[o], bb = bv[o];
      const float tv = (tadd != nullptr) ? tadd[(long long)b * O + o] : 0.f;
      float r[8];
#pragma unroll
      for (int nj = 0; nj < 8; ++nj) r[nj] = lrelu(fmaf(s, acc[oi][nj] + tv, bb));
      float4 v0 = {r[0], r[1], r[2], r[3]};
      float4 v1 = {r[4], r[5], r[6], r[7]};
      float* op = out + ((long long)b * O + o) * PTS + n0 + ng * 8;
      *(float4*)op = v0;
      *(float4*)(op + 4) = v1;
    }
  } else {
    float so[4], bo[4];
#pragma unroll
    for (int oi = 0; oi < 4; ++oi) { so[oi] = sv[o0 + og * 4 + oi]; bo[oi] = bv[o0 + og * 4 + oi]; }
#pragma unroll
    for (int nj = 0; nj < 8; ++nj) {
      const int n = n0 + ng * 8 + nj;
      float4 v;
      v.x = lrelu(fmaf(so[0], acc[0][nj], bo[0]));
      v.y = lrelu(fmaf(so[1], acc[1][nj], bo[1]));
      v.z = lrelu(fmaf(so[2], acc[2][nj], bo[2]));
      v.w = lrelu(fmaf(so[3], acc[3][nj], bo[3]));
      *(float4*)&out[((long long)b * PTS + n) * O + o0 + og * 4] = v;
    }
  }
}

// ---------------- finalize global max g[b][1024] ----------------
__global__ __launch_bounds__(256) void gfin_k(const float* __restrict__ gp, float* __restrict__ g) {
  const int i = blockIdx.x * 256 + threadIdx.x;
  const int b = i >> 10, o = i & 1023;
  float m = -3.4e38f;
#pragma unroll 4
  for (int t = 0; t < 16; ++t) m = fmaxf(m, gp[((long long)b * 16 + t) * 1024 + o]);
  g[i] = m;
}

// ---------------- tvec[b][256] = Wf1[:, :1024] * g + Wf1[:, 1024:1088] * cv ----------------
__global__ __launch_bounds__(256) void tvec_k(
    const float* __restrict__ cls, const float* __restrict__ wc, const float* __restrict__ sc,
    const float* __restrict__ bc, const float* __restrict__ g, const float* __restrict__ wf1,
    float* __restrict__ tvec) {
  __shared__ float gs[1024];
  __shared__ float cvs[64];
  const int b = blockIdx.x, tid = threadIdx.x;
  for (int q = tid; q < 1024; q += 256) gs[q] = g[b * 1024 + q];
  if (tid < 64) {
    float a = 0.f;
#pragma unroll
    for (int j = 0; j < 16; ++j) a = fmaf(wc[tid * 16 + j], cls[b * 16 + j], a);
    cvs[tid] = lrelu(fmaf(sc[tid], a, bc[tid]));
  }
  __syncthreads();
  const float* wr = wf1 + (long long)tid * 1280;
  float a0 = 0.f, a1 = 0.f;
  for (int c = 0; c < 1024; c += 4) {
    const float4 w = *(const float4*)&wr[c];
    const float4 gv = *(const float4*)&gs[c];
    a0 = fmaf(w.x, gv.x, a0); a1 = fmaf(w.y, gv.y, a1);
    a0 = fmaf(w.z, gv.z, a0); a1 = fmaf(w.w, gv.w, a1);
  }
#pragma unroll
  for (int c = 0; c < 64; c += 4) {
    const float4 w = *(const float4*)&wr[1024 + c];
    const float4 cv = *(const float4*)&cvs[c];
    a0 = fmaf(w.x, cv.x, a0); a1 = fmaf(w.y, cv.y, a1);
    a0 = fmaf(w.z, cv.z, a0); a1 = fmaf(w.w, cv.w, a1);
  }
  tvec[b * 256 + tid] = a0 + a1;
}

// ---------------- logits (50x128) + log_softmax + [B][N][50] store ----------------
__global__ __launch_bounds__(256) void logits_k(const float* __restrict__ f3t, const float* __restrict__ wf4,
                                                float* __restrict__ out) {
  __shared__ float wT[6464];   // wT[c*50 + o], padded
  const int tid = threadIdx.x, lane = tid & 63, wv = tid >> 6;
  for (int q = tid; q < 6400; q += 256) {
    const int o = q >> 7, c = q & 127;
    wT[c * 50 + o] = wf4[q];
  }
  __syncthreads();
  const long long pn = (long long)blockIdx.x * 4 + wv;
  const float lo = f3t[pn * 128 + lane], hi = f3t[pn * 128 + 64 + lane];
  float a0 = 0.f, a1 = 0.f;
#pragma unroll
  for (int c = 0; c < 64; c += 2) {
    a0 = fmaf(wT[c * 50 + lane], rl(lo, c), a0);
    a1 = fmaf(wT[(c + 1) * 50 + lane], rl(lo, c + 1), a1);
  }
#pragma unroll
  for (int c = 0; c < 64; c += 2) {
    a0 = fmaf(wT[(64 + c) * 50 + lane], rl(hi, c), a0);
    a1 = fmaf(wT[(65 + c) * 50 + lane], rl(hi, c + 1), a1);
  }
  const float logit = (lane < 50) ? (a0 + a1) : -3.4e38f;
  float M = logit;
#pragma unroll
  for (int mask = 1; mask < 64; mask <<= 1) M = fmaxf(M, __shfl_xor(M, mask, 64));
  const float ex = (lane < 50) ? __expf(logit - M) : 0.f;
  float S = ex;
#pragma unroll
  for (int mask = 1; mask < 64; mask <<= 1) S += __shfl_xor(S, mask, 64);
  if (lane < 50) out[pn * 50 + lane] = logit - M - __logf(S);
}

extern "C" void kernel_launch(void* const* d_in, const int* in_sizes, int n_in,
                              void* d_out, int out_size, void* d_ws, size_t ws_size,
                              hipStream_t stream) {
  (void)in_sizes; (void)n_in; (void)out_size; (void)ws_size;
  const float* points = (const float*)d_in[0];
  const float* cls = (const float*)d_in[1];
  const float* w1 = (const float*)d_in[2];
  const float* s1 = (const float*)d_in[3];
  const float* b1 = (const float*)d_in[4];
  const float* w2 = (const float*)d_in[5];
  const float* s2 = (const float*)d_in[6];
  const float* b2 = (const float*)d_in[7];
  const float* w3 = (const float*)d_in[8];
  const float* s3 = (const float*)d_in[9];
  const float* b3 = (const float*)d_in[10];
  const float* w4 = (const float*)d_in[11];
  const float* s4 = (const float*)d_in[12];
  const float* b4 = (const float*)d_in[13];
  const float* w5 = (const float*)d_in[14];
  const float* s5 = (const float*)d_in[15];
  const float* b5 = (const float*)d_in[16];
  const float* w6 = (const float*)d_in[17];
  const float* s6 = (const float*)d_in[18];
  const float* b6 = (const float*)d_in[19];
  const float* wc = (const float*)d_in[20];
  const float* sc = (const float*)d_in[21];
  const float* bc = (const float*)d_in[22];
  const float* wf1 = (const float*)d_in[23];
  const float* sf1 = (const float*)d_in[24];
  const float* bf1 = (const float*)d_in[25];
  const float* wf2 = (const float*)d_in[26];
  const float* sf2 = (const float*)d_in[27];
  const float* bf2 = (const float*)d_in[28];
  const float* wf3 = (const float*)d_in[29];
  const float* sf3 = (const float*)d_in[30];
  const float* bf3 = (const float*)d_in[31];
  const float* wf4 = (const float*)d_in[32];
  float* out = (float*)d_out;
  float* ws = (float*)d_ws;

  // workspace layout (floats); f2c aliases x1t..x2c (dead), f3t aliases f1c (dead)
  float* x1t = ws;
  float* x1c = ws + 2097152LL;
  float* x2t = ws + 4194304LL;
  float* x2c = ws + 6291456LL;
  float* x3c = ws + 8388608LL;
  float* f1c = ws + 10485760LL;
  float* f2c = ws;
  float* f3t = ws + 10485760LL;
  int* idx = (int*)(ws + 18874368LL);
  float* gpart = ws + 19529728LL;
  float* g = ws + 19791872LL;
  float* tvec = ws + 19808256LL;

  {
    void (*k3)(const float*, int*) = knn_k<3>;
    void (*k64)(const float*, int*) = knn_k<64>;
    (void)hipFuncSetAttribute(reinterpret_cast<const void*>(k3), hipFuncAttributeMaxDynamicSharedMemorySize, 160 * 1024);
    (void)hipFuncSetAttribute(reinterpret_cast<const void*>(k64), hipFuncAttributeMaxDynamicSharedMemorySize, 160 * 1024);
  }
  const int lds3 = (8 * 2112 + 4 * 260 + 8 * 8) * 4;     // 72000 B
  const int lds64 = (8 * 2112 + 64 * 260 + 8 * 68) * 4;  // 136320 B

  SrcTab tabX{{x1c, x2c, x3c, nullptr}, {64LL * PTS, 64LL * PTS, 64LL * PTS, 0}};
  SrcTab tabF1{{f1c, f1c + 64 * PTS, f1c + 128 * PTS, f1c + 192 * PTS},
               {256LL * PTS, 256LL * PTS, 256LL * PTS, 256LL * PTS}};
  SrcTab tabF2{{f2c, f2c + 64 * PTS, f2c + 128 * PTS, f2c + 192 * PTS},
               {256LL * PTS, 256LL * PTS, 256LL * PTS, 256LL * PTS}};

  knn_k<3><<<4096, 256, lds3, stream>>>(points, idx);
  edge1_k<<<2048, 64, 0, stream>>>(points, idx, w1, s1, b1, w2, s2, b2, x1t, x1c);
  knn_k<64><<<4096, 256, lds64, stream>>>(x1c, idx);
  edge2_k<<<2048, 64, 0, stream>>>(x1t, idx, w3, s3, b3, w4, s4, b4, x2t, x2c);
  knn_k<64><<<4096, 256, lds64, stream>>>(x2c, idx);
  edge3_k<<<2048, 64, 0, stream>>>(x2t, idx, w5, s5, b5, x3c);
  gemm_k<1><<<dim3(16, 16, 16), 256, 0, stream>>>(w6, 192, 0, tabX, 192, s6, b6, nullptr, gpart, 1024);
  gfin_k<<<64, 256, 0, stream>>>(gpart, g);
  tvec_k<<<16, 256, 0, stream>>>(cls, wc, sc, bc, g, wf1, tvec);
  gemm_k<0><<<dim3(16, 4, 16), 256, 0, stream>>>(wf1, 1280, 1088, tabX, 192, sf1, bf1, tvec, f1c, 256);
  gemm_k<0><<<dim3(16, 4, 16), 256, 0, stream>>>(wf2, 256, 0, tabF1, 256, sf2, bf2, nullptr, f2c, 256);
  gemm_k<2><<<dim3(16, 2, 16), 256, 0, stream>>>(wf3, 256, 0, tabF2, 256, sf3, bf3, nullptr, f3t, 128);
  logits_k<<<8192, 256, 0, stream>>>(f3t, wf4, out);
}

// Round 2
// 2328.271 us; speedup vs baseline: 2.1117x; 2.1117x over previous
//
#include <hip/hip_runtime.h>

constexpr int PTS = 2048;   // points per batch
constexpr int KK  = 20;     // knn

static __device__ __forceinline__ float lrelu(float x) { return x >= 0.f ? x : 0.2f * x; }
static __device__ __forceinline__ float rl(float v, int l) {
  return __int_as_float(__builtin_amdgcn_readlane(__float_as_int(v), l));
}
static __device__ __forceinline__ void argmax64(float& v, int& m) {
#pragma unroll
  for (int mask = 1; mask < 64; mask <<= 1) {
    float ov = __shfl_xor(v, mask, 64);
    int om = __shfl_xor(m, mask, 64);
    if (ov > v || (ov == v && om < m)) { v = ov; m = om; }
  }
}

// ---------------- xx[b][m] = sum_c x[c][m]^2 ----------------
template <int C>
__global__ __launch_bounds__(256) void xnorm_k(const float* __restrict__ x, float* __restrict__ xx) {
  const int i = blockIdx.x * 256 + threadIdx.x;  // b*2048 + m
  const int b = i >> 11, m = i & 2047;
  float s = 0.f;
#pragma unroll
  for (int c = 0; c < C; ++c) {
    const float v = x[((long long)b * C + c) * PTS + m];
    s = fmaf(v, v, s);
  }
  xx[i] = s;
}

// ---------------- dist GEMM: D[bl][n][m] = 2*sum_c x[c][n]x[c][m] - xx[m] ----------------
// grid (mt=16, nt=16, nb); 128x128 tile, 8x8 per thread.
template <int C>
__global__ __launch_bounds__(256) void dist_k(const float* __restrict__ x, const float* __restrict__ xx,
                                              float* __restrict__ D, int bo) {
  constexpr int CP = (C == 3) ? 4 : 32;
  __shared__ float xn[CP * 132];
  __shared__ float xm[CP * 132];
  const int tid = threadIdx.x;
  const int mt = blockIdx.x, nt = blockIdx.y, bl = blockIdx.z;
  const int b = bo + bl;
  const int n0 = nt * 128, m0 = mt * 128;
  const int og = tid & 15, ng = tid >> 4;
  float acc[8][8] = {};
  for (int cc = 0; cc < C; cc += CP) {
    __syncthreads();
    for (int q = tid; q < CP * 32; q += 256) {
      const int c = q >> 5, n4 = (q & 31) << 2;
      float4 vn = {0.f, 0.f, 0.f, 0.f}, vm = {0.f, 0.f, 0.f, 0.f};
      if (cc + c < C) {
        vn = *(const float4*)&x[((long long)b * C + cc + c) * PTS + n0 + n4];
        vm = *(const float4*)&x[((long long)b * C + cc + c) * PTS + m0 + n4];
      }
      *(float4*)&xn[c * 132 + n4] = vn;
      *(float4*)&xm[c * 132 + n4] = vm;
    }
    __syncthreads();
#pragma unroll
    for (int c = 0; c < CP; ++c) {
      const float4 a0 = *(const float4*)&xn[c * 132 + ng * 8];
      const float4 a1 = *(const float4*)&xn[c * 132 + ng * 8 + 4];
      const float4 b0 = *(const float4*)&xm[c * 132 + og * 8];
      const float4 b1 = *(const float4*)&xm[c * 132 + og * 8 + 4];
      const float na[8] = {a0.x, a0.y, a0.z, a0.w, a1.x, a1.y, a1.z, a1.w};
      const float ma[8] = {b0.x, b0.y, b0.z, b0.w, b1.x, b1.y, b1.z, b1.w};
#pragma unroll
      for (int i = 0; i < 8; ++i)
#pragma unroll
        for (int j = 0; j < 8; ++j) acc[i][j] = fmaf(na[i], ma[j], acc[i][j]);
    }
  }
  const float4 xx0 = *(const float4*)&xx[(long long)b * PTS + m0 + og * 8];
  const float4 xx1 = *(const float4*)&xx[(long long)b * PTS + m0 + og * 8 + 4];
  const float xa[8] = {xx0.x, xx0.y, xx0.z, xx0.w, xx1.x, xx1.y, xx1.z, xx1.w};
#pragma unroll
  for (int i = 0; i < 8; ++i) {
    float r[8];
#pragma unroll
    for (int j = 0; j < 8; ++j) r[j] = 2.f * acc[i][j] - xa[j];
    float* op = D + ((long long)bl * PTS + n0 + ng * 8 + i) * PTS + m0 + og * 8;
    float4 v0 = {r[0], r[1], r[2], r[3]};
    float4 v1 = {r[4], r[5], r[6], r[7]};
    *(float4*)op = v0;
    *(float4*)(op + 4) = v1;
  }
}

// ---------------- top-20 selection: 1 wave per point, 4 points/block ----------------
__global__ __launch_bounds__(256) void select_k(const float* __restrict__ D, int* __restrict__ idxout, int bo) {
  __shared__ float sh[4 * 2112];
  const int tid = threadIdx.x, lane = tid & 63, wid = tid >> 6;
  const long long pn = (long long)blockIdx.x * 4 + wid;  // chunk-local point id
  const int bl = (int)(pn >> 11);
  const int n = (int)(pn & 2047);
  const int b = bo + bl;
  float* dp = sh + wid * 2112;
  const float* row = D + pn * PTS;
#pragma unroll
  for (int q = 0; q < 8; ++q) {
    const int m = q * 256 + lane * 4;
    const float4 v = *(const float4*)&row[m];
    dp[((m + 0) & 63) * 33 + ((m + 0) >> 6)] = v.x;
    dp[((m + 1) & 63) * 33 + ((m + 1) >> 6)] = v.y;
    dp[((m + 2) & 63) * 33 + ((m + 2) >> 6)] = v.z;
    dp[((m + 3) & 63) * 33 + ((m + 3) >> 6)] = v.w;
  }
  asm volatile("s_waitcnt lgkmcnt(0)" ::: "memory");
  float bv = -3.4e38f; int bm = 1 << 29;
#pragma unroll 4
  for (int j = 0; j < 32; ++j) {
    float v = dp[lane * 33 + j];
    if (v > bv) { bv = v; bm = lane + (j << 6); }  // ascending m: strict > keeps lowest idx
  }
  int keep = 0;
  for (int r = 0; r < KK; ++r) {
    float cv = bv; int cm = bm;
    argmax64(cv, cm);
    if (lane == r) keep = cm;
    const int sm = cm & 63;
    if (lane == 0) dp[sm * 33 + (cm >> 6)] = -3.4e38f;  // persistent invalidation
    asm volatile("s_waitcnt lgkmcnt(0)" ::: "memory");
    const int jj = lane & 31;  // all-lane rescan of seg sm
    float v2 = dp[sm * 33 + jj];
    int m2 = sm + (jj << 6);
    if (m2 == cm) v2 = -3.4e38f;
    argmax64(v2, m2);
    if (lane == sm) { bv = v2; bm = m2; }
  }
  if (lane < KK) idxout[((long long)b * PTS + n) * KK + lane] = keep;
}

// ---------------- EdgeConv block 1 (C=3 -> 64 -> 64, max over k) ----------------
__global__ __launch_bounds__(64, 2) void edge1_k(
    const float* __restrict__ pts, const int* __restrict__ idxb,
    const float* __restrict__ w1, const float* __restrict__ s1, const float* __restrict__ b1,
    const float* __restrict__ w2, const float* __restrict__ s2, const float* __restrict__ b2,
    float* __restrict__ x1t, float* __restrict__ x1c) {
  const int lane = threadIdx.x;
  const int bid = blockIdx.x;
  const int b = bid >> 7, n0 = (bid & 127) << 4;
  float w1r[6];
#pragma unroll
  for (int k = 0; k < 6; ++k) w1r[k] = w1[lane * 6 + k];
  float w2r[64];
#pragma unroll
  for (int k = 0; k < 16; ++k) {
    const float4 v = *(const float4*)&w2[lane * 64 + 4 * k];
    w2r[4 * k] = v.x; w2r[4 * k + 1] = v.y; w2r[4 * k + 2] = v.z; w2r[4 * k + 3] = v.w;
  }
  const float s1o = s1[lane], b1o = b1[lane], s2o = s2[lane], b2o = b2[lane];
  const float* pb = pts + (long long)b * 3 * PTS;
  for (int pt = 0; pt < 16; ++pt) {
    const int n = n0 + pt;
    const float px = pb[n], py = pb[PTS + n], pz = pb[2 * PTS + n];
    const float cc = w1r[3] * px + w1r[4] * py + w1r[5] * pz;
    float gm = -3.4e38f;
    for (int j = 0; j < KK; ++j) {
      const int m = idxb[((long long)b * PTS + n) * KK + j];
      const float dx = pb[m] - px, dy = pb[PTS + m] - py, dz = pb[2 * PTS + m] - pz;
      const float acc = fmaf(w1r[0], dx, fmaf(w1r[1], dy, fmaf(w1r[2], dz, cc)));
      const float y1 = lrelu(fmaf(s1o, acc, b1o));
      float d0 = 0.f, d1 = 0.f;
#pragma unroll
      for (int c = 0; c < 64; c += 2) {
        d0 = fmaf(w2r[c], rl(y1, c), d0);
        d1 = fmaf(w2r[c + 1], rl(y1, c + 1), d1);
      }
      gm = fmaxf(gm, lrelu(fmaf(s2o, d0 + d1, b2o)));
    }
    x1t[((long long)b * PTS + n) * 64 + lane] = gm;
    x1c[((long long)b * 64 + lane) * PTS + n] = gm;
  }
}

// ---------------- EdgeConv block 2 (C=64 -> 128-in conv -> 64 -> 64, max) ----------------
__global__ __launch_bounds__(64, 2) void edge2_k(
    const float* __restrict__ xt, const int* __restrict__ idxb,
    const float* __restrict__ w3, const float* __restrict__ s3, const float* __restrict__ b3,
    const float* __restrict__ w4, const float* __restrict__ s4, const float* __restrict__ b4,
    float* __restrict__ x2t, float* __restrict__ x2c) {
  const int lane = threadIdx.x;
  const int bid = blockIdx.x;
  const int b = bid >> 7, n0 = (bid & 127) << 4;
  float wa[64], wb[64], w4r[64];
#pragma unroll
  for (int k = 0; k < 16; ++k) {
    float4 v = *(const float4*)&w3[lane * 128 + 4 * k];
    wa[4 * k] = v.x; wa[4 * k + 1] = v.y; wa[4 * k + 2] = v.z; wa[4 * k + 3] = v.w;
    v = *(const float4*)&w3[lane * 128 + 64 + 4 * k];
    wb[4 * k] = v.x; wb[4 * k + 1] = v.y; wb[4 * k + 2] = v.z; wb[4 * k + 3] = v.w;
    v = *(const float4*)&w4[lane * 64 + 4 * k];
    w4r[4 * k] = v.x; w4r[4 * k + 1] = v.y; w4r[4 * k + 2] = v.z; w4r[4 * k + 3] = v.w;
  }
  const float s3o = s3[lane], b3o = b3[lane], s4o = s4[lane], b4o = b4[lane];
  for (int pt = 0; pt < 16; ++pt) {
    const int n = n0 + pt;
    const float ctro = xt[((long long)b * PTS + n) * 64 + lane];
    float c0 = 0.f, c1 = 0.f;
#pragma unroll
    for (int c = 0; c < 64; c += 2) {
      c0 = fmaf(wb[c], rl(ctro, c), c0);
      c1 = fmaf(wb[c + 1], rl(ctro, c + 1), c1);
    }
    const float cc = c0 + c1;
    float gm = -3.4e38f;
    for (int j = 0; j < KK; ++j) {
      const int m = idxb[((long long)b * PTS + n) * KK + j];
      const float df = xt[((long long)b * PTS + m) * 64 + lane] - ctro;
      float a0 = cc, a1 = 0.f;
#pragma unroll
      for (int c = 0; c < 64; c += 2) {
        a0 = fmaf(wa[c], rl(df, c), a0);
        a1 = fmaf(wa[c + 1], rl(df, c + 1), a1);
      }
      const float y1 = lrelu(fmaf(s3o, a0 + a1, b3o));
      float d0 = 0.f, d1 = 0.f;
#pragma unroll
      for (int c = 0; c < 64; c += 2) {
        d0 = fmaf(w4r[c], rl(y1, c), d0);
        d1 = fmaf(w4r[c + 1], rl(y1, c + 1), d1);
      }
      gm = fmaxf(gm, lrelu(fmaf(s4o, d0 + d1, b4o)));
    }
    x2t[((long long)b * PTS + n) * 64 + lane] = gm;
    x2c[((long long)b * 64 + lane) * PTS + n] = gm;
  }
}

// ---------------- EdgeConv block 3 (single conv 128-in -> 64, max) ----------------
__global__ __launch_bounds__(64, 2) void edge3_k(
    const float* __restrict__ xt, const int* __restrict__ idxb,
    const float* __restrict__ w5, const float* __restrict__ s5, const float* __restrict__ b5,
    float* __restrict__ x3c) {
  const int lane = threadIdx.x;
  const int bid = blockIdx.x;
  const int b = bid >> 7, n0 = (bid & 127) << 4;
  float wa[64], wb[64];
#pragma unroll
  for (int k = 0; k < 16; ++k) {
    float4 v = *(const float4*)&w5[lane * 128 + 4 * k];
    wa[4 * k] = v.x; wa[4 * k + 1] = v.y; wa[4 * k + 2] = v.z; wa[4 * k + 3] = v.w;
    v = *(const float4*)&w5[lane * 128 + 64 + 4 * k];
    wb[4 * k] = v.x; wb[4 * k + 1] = v.y; wb[4 * k + 2] = v.z; wb[4 * k + 3] = v.w;
  }
  const float s5o = s5[lane], b5o = b5[lane];
  for (int pt = 0; pt < 16; ++pt) {
    const int n = n0 + pt;
    const float ctro = xt[((long long)b * PTS + n) * 64 + lane];
    float c0 = 0.f, c1 = 0.f;
#pragma unroll
    for (int c = 0; c < 64; c += 2) {
      c0 = fmaf(wb[c], rl(ctro, c), c0);
      c1 = fmaf(wb[c + 1], rl(ctro, c + 1), c1);
    }
    const float cc = c0 + c1;
    float gm = -3.4e38f;
    for (int j = 0; j < KK; ++j) {
      const int m = idxb[((long long)b * PTS + n) * KK + j];
      const float df = xt[((long long)b * PTS + m) * 64 + lane] - ctro;
      float a0 = cc, a1 = 0.f;
#pragma unroll
      for (int c = 0; c < 64; c += 2) {
        a0 = fmaf(wa[c], rl(df, c), a0);
        a1 = fmaf(wa[c + 1], rl(df, c + 1), a1);
      }
      gm = fmaxf(gm, lrelu(fmaf(s5o, a0 + a1, b5o)));
    }
    x3c[((long long)b * 64 + lane) * PTS + n] = gm;
  }
}

// ---------------- generic f32 GEMM: out = affine_lrelu(W[O,C] * X[C,PTS]) ----------------
// MODE 0: store [b][O][PTS] (+optional per-(b,o) pre-bias tadd); MODE 1: max over n -> gpart; MODE 2: store [b][PTS][O]
struct SrcTab { const float* p[4]; long long bs[4]; };

template <int MODE>
__global__ __launch_bounds__(256) void gemm_k(
    const float* __restrict__ W, int wstride, int c0, SrcTab tab, int C,
    const float* __restrict__ sv, const float* __restrict__ bv, const float* __restrict__ tadd,
    float* __restrict__ out, int O) {
  __shared__ float wT[32 * 68];   // [c][o]
  __shared__ float xT[32 * 132];  // [c][n]
  const int tid = threadIdx.x;
  const int nt = blockIdx.x, ot = blockIdx.y, b = blockIdx.z;
  const int n0 = nt * 128, o0 = ot * 64;
  const int og = tid & 15, ng = tid >> 4;
  float acc[4][8] = {};
  for (int cc = 0; cc < C; cc += 32) {
    __syncthreads();
    for (int q = tid; q < 512; q += 256) {
      const int row = q >> 3, c4 = (q & 7) << 2;
      const float4 v = *(const float4*)&W[(long long)(o0 + row) * wstride + c0 + cc + c4];
      wT[(c4 + 0) * 68 + row] = v.x;
      wT[(c4 + 1) * 68 + row] = v.y;
      wT[(c4 + 2) * 68 + row] = v.z;
      wT[(c4 + 3) * 68 + row] = v.w;
    }
    for (int q = tid; q < 1024; q += 256) {
      const int c = q >> 5, n4 = (q & 31) << 2;
      const int cg = cc + c;
      const float4 v = *(const float4*)(tab.p[cg >> 6] + tab.bs[cg >> 6] * b + (long long)(cg & 63) * PTS + n0 + n4);
      *(float4*)&xT[c * 132 + n4] = v;
    }
    __syncthreads();
#pragma unroll 8
    for (int c = 0; c < 32; ++c) {
      const float4 av = *(const float4*)&wT[c * 68 + og * 4];
      const float4 x0 = *(const float4*)&xT[c * 132 + ng * 8];
      const float4 x1 = *(const float4*)&xT[c * 132 + ng * 8 + 4];
      const float aa[4] = {av.x, av.y, av.z, av.w};
      const float xx[8] = {x0.x, x0.y, x0.z, x0.w, x1.x, x1.y, x1.z, x1.w};
#pragma unroll
      for (int oi = 0; oi < 4; ++oi)
#pragma unroll
        for (int nj = 0; nj < 8; ++nj) acc[oi][nj] = fmaf(aa[oi], xx[nj], acc[oi][nj]);
    }
  }
  if (MODE == 1) {
    __syncthreads();
    float* red = xT;
#pragma unroll
    for (int oi = 0; oi < 4; ++oi) {
      const int o = o0 + og * 4 + oi;
      const float s = sv[o], bb = bv[o];
      float pm = -3.4e38f;
#pragma unroll
      for (int nj = 0; nj < 8; ++nj) pm = fmaxf(pm, lrelu(fmaf(s, acc[oi][nj], bb)));
      red[(og * 4 + oi) * 16 + ng] = pm;
    }
    __syncthreads();
    if (tid < 64) {
      float m = red[tid * 16];
#pragma unroll
      for (int k = 1; k < 16; ++k) m = fmaxf(m, red[tid * 16 + k]);
      out[((long long)b * 16 + nt) * 1024 + o0 + tid] = m;
    }
  } else if (MODE == 0) {
#pragma unroll
    for (int oi = 0; oi < 4; ++oi) {
      const int o = o0 + og * 4 + oi;
      const float s = sv[o], bb = bv[o];
      const float tv = (tadd != nullptr) ? tadd[(long long)b * O + o] : 0.f;
      float r[8];
#pragma unroll
      for (int nj = 0; nj < 8; ++nj) r[nj] = lrelu(fmaf(s, acc[oi][nj] + tv, bb));
      float4 v0 = {r[0], r[1], r[2], r[3]};
      float4 v1 = {r[4], r[5], r[6], r[7]};
      float* op = out + ((long long)b * O + o) * PTS + n0 + ng * 8;
      *(float4*)op = v0;
      *(float4*)(op + 4) = v1;
    }
  } else {
    float so[4], bo[4];
#pragma unroll
    for (int oi = 0; oi < 4; ++oi) { so[oi] = sv[o0 + og * 4 + oi]; bo[oi] = bv[o0 + og * 4 + oi]; }
#pragma unroll
    for (int nj = 0; nj < 8; ++nj) {
      const int n = n0 + ng * 8 + nj;
      float4 v;
      v.x = lrelu(fmaf(so[0], acc[0][nj], bo[0]));
      v.y = lrelu(fmaf(so[1], acc[1][nj], bo[1]));
      v.z = lrelu(fmaf(so[2], acc[2][nj], bo[2]));
      v.w = lrelu(fmaf(so[3], acc[3][nj], bo[3]));
      *(float4*)&out[((long long)b * PTS + n) * O + o0 + og * 4] = v;
    }
  }
}

// ---------------- finalize global max g[b][1024] ----------------
__global__ __launch_bounds__(256) void gfin_k(const float* __restrict__ gp, float* __restrict__ g) {
  const int i = blockIdx.x * 256 + threadIdx.x;
  const int b = i >> 10, o = i & 1023;
  float m = -3.4e38f;
#pragma unroll 4
  for (int t = 0; t < 16; ++t) m = fmaxf(m, gp[((long long)b * 16 + t) * 1024 + o]);
  g[i] = m;
}

// ---------------- tvec[b][256] = Wf1[:, :1024] * g + Wf1[:, 1024:1088] * cv ----------------
__global__ __launch_bounds__(256) void tvec_k(
    const float* __restrict__ cls, const float* __restrict__ wc, const float* __restrict__ sc,
    const float* __restrict__ bc, const float* __restrict__ g, const float* __restrict__ wf1,
    float* __restrict__ tvec) {
  __shared__ float gs[1024];
  __shared__ float cvs[64];
  const int b = blockIdx.x, tid = threadIdx.x;
  for (int q = tid; q < 1024; q += 256) gs[q] = g[b * 1024 + q];
  if (tid < 64) {
    float a = 0.f;
#pragma unroll
    for (int j = 0; j < 16; ++j) a = fmaf(wc[tid * 16 + j], cls[b * 16 + j], a);
    cvs[tid] = lrelu(fmaf(sc[tid], a, bc[tid]));
  }
  __syncthreads();
  const float* wr = wf1 + (long long)tid * 1280;
  float a0 = 0.f, a1 = 0.f;
  for (int c = 0; c < 1024; c += 4) {
    const float4 w = *(const float4*)&wr[c];
    const float4 gv = *(const float4*)&gs[c];
    a0 = fmaf(w.x, gv.x, a0); a1 = fmaf(w.y, gv.y, a1);
    a0 = fmaf(w.z, gv.z, a0); a1 = fmaf(w.w, gv.w, a1);
  }
#pragma unroll
  for (int c = 0; c < 64; c += 4) {
    const float4 w = *(const float4*)&wr[1024 + c];
    const float4 cv = *(const float4*)&cvs[c];
    a0 = fmaf(w.x, cv.x, a0); a1 = fmaf(w.y, cv.y, a1);
    a0 = fmaf(w.z, cv.z, a0); a1 = fmaf(w.w, cv.w, a1);
  }
  tvec[b * 256 + tid] = a0 + a1;
}

// ---------------- logits (50x128) + log_softmax + [B][N][50] store ----------------
__global__ __launch_bounds__(256) void logits_k(const float* __restrict__ f3t, const float* __restrict__ wf4,
                                                float* __restrict__ out) {
  __shared__ float wT[6464];   // wT[c*50 + o], padded
  const int tid = threadIdx.x, lane = tid & 63, wv = tid >> 6;
  for (int q = tid; q < 6400; q += 256) {
    const int o = q >> 7, c = q & 127;
    wT[c * 50 + o] = wf4[q];
  }
  __syncthreads();
  const long long pn = (long long)blockIdx.x * 4 + wv;
  const float lo = f3t[pn * 128 + lane], hi = f3t[pn * 128 + 64 + lane];
  float a0 = 0.f, a1 = 0.f;
#pragma unroll
  for (int c = 0; c < 64; c += 2) {
    a0 = fmaf(wT[c * 50 + lane], rl(lo, c), a0);
    a1 = fmaf(wT[(c + 1) * 50 + lane], rl(lo, c + 1), a1);
  }
#pragma unroll
  for (int c = 0; c < 64; c += 2) {
    a0 = fmaf(wT[(64 + c) * 50 + lane], rl(hi, c), a0);
    a1 = fmaf(wT[(65 + c) * 50 + lane], rl(hi, c + 1), a1);
  }
  const float logit = (lane < 50) ? (a0 + a1) : -3.4e38f;
  float M = logit;
#pragma unroll
  for (int mask = 1; mask < 64; mask <<= 1) M = fmaxf(M, __shfl_xor(M, mask, 64));
  const float ex = (lane < 50) ? __expf(logit - M) : 0.f;
  float S = ex;
#pragma unroll
  for (int mask = 1; mask < 64; mask <<= 1) S += __shfl_xor(S, mask, 64);
  if (lane < 50) out[pn * 50 + lane] = logit - M - __logf(S);
}

extern "C" void kernel_launch(void* const* d_in, const int* in_sizes, int n_in,
                              void* d_out, int out_size, void* d_ws, size_t ws_size,
                              hipStream_t stream) {
  (void)in_sizes; (void)n_in; (void)out_size;
  const float* points = (const float*)d_in[0];
  const float* cls = (const float*)d_in[1];
  const float* w1 = (const float*)d_in[2];
  const float* s1 = (const float*)d_in[3];
  const float* b1 = (const float*)d_in[4];
  const float* w2 = (const float*)d_in[5];
  const float* s2 = (const float*)d_in[6];
  const float* b2 = (const float*)d_in[7];
  const float* w3 = (const float*)d_in[8];
  const float* s3 = (const float*)d_in[9];
  const float* b3 = (const float*)d_in[10];
  const float* w4 = (const float*)d_in[11];
  const float* s4 = (const float*)d_in[12];
  const float* b4 = (const float*)d_in[13];
  const float* w5 = (const float*)d_in[14];
  const float* s5 = (const float*)d_in[15];
  const float* b5 = (const float*)d_in[16];
  const float* w6 = (const float*)d_in[17];
  const float* s6 = (const float*)d_in[18];
  const float* b6 = (const float*)d_in[19];
  const float* wc = (const float*)d_in[20];
  const float* sc = (const float*)d_in[21];
  const float* bc = (const float*)d_in[22];
  const float* wf1 = (const float*)d_in[23];
  const float* sf1 = (const float*)d_in[24];
  const float* bf1 = (const float*)d_in[25];
  const float* wf2 = (const float*)d_in[26];
  const float* sf2 = (const float*)d_in[27];
  const float* bf2 = (const float*)d_in[28];
  const float* wf3 = (const float*)d_in[29];
  const float* sf3 = (const float*)d_in[30];
  const float* bf3 = (const float*)d_in[31];
  const float* wf4 = (const float*)d_in[32];
  float* out = (float*)d_out;
  float* ws = (float*)d_ws;

  // workspace layout (floats); f2c aliases x1t..x2c (dead), f3t aliases f1c (dead)
  float* x1t = ws;
  float* x1c = ws + 2097152LL;
  float* x2t = ws + 4194304LL;
  float* x2c = ws + 6291456LL;
  float* x3c = ws + 8388608LL;
  float* f1c = ws + 10485760LL;
  float* f2c = ws;
  float* f3t = ws + 10485760LL;
  int* idx = (int*)(ws + 18874368LL);
  float* gpart = ws + 19529728LL;
  float* g = ws + 19791872LL;
  float* tvec = ws + 19808256LL;
  float* xxb = ws + 19812352LL;   // [B][2048] squared norms (ends 19845120)

  // D scratch: pick batch-chunk NB from ws_size (deterministic). Fallback NB=2
  // aliases D into regions provably dead during each knn (fits round-1-proven 80MB).
  const long long DBATCH = (long long)PTS * PTS;          // 4194304 floats
  const long long baseFl = 20971520LL;                    // 80 MiB mark (floats)
  int NB; long long doff[3];
  if (ws_size >= (size_t)(baseFl + 16 * DBATCH) * 4) { NB = 16; doff[0] = doff[1] = doff[2] = baseFl; }
  else if (ws_size >= (size_t)(baseFl + 4 * DBATCH) * 4) { NB = 4; doff[0] = doff[1] = doff[2] = baseFl; }
  else { NB = 2; doff[0] = 0; doff[1] = 4194304LL; doff[2] = 8388608LL; }

  SrcTab tabX{{x1c, x2c, x3c, nullptr}, {64LL * PTS, 64LL * PTS, 64LL * PTS, 0}};
  SrcTab tabF1{{f1c, f1c + 64 * PTS, f1c + 128 * PTS, f1c + 192 * PTS},
               {256LL * PTS, 256LL * PTS, 256LL * PTS, 256LL * PTS}};
  SrcTab tabF2{{f2c, f2c + 64 * PTS, f2c + 128 * PTS, f2c + 192 * PTS},
               {256LL * PTS, 256LL * PTS, 256LL * PTS, 256LL * PTS}};

  // ---- kNN 1 (C=3 on points) ----
  xnorm_k<3><<<128, 256, 0, stream>>>(points, xxb);
  for (int bo = 0; bo < 16; bo += NB) {
    const int nb = (16 - bo < NB) ? (16 - bo) : NB;
    dist_k<3><<<dim3(16, 16, nb), 256, 0, stream>>>(points, xxb, ws + doff[0], bo);
    select_k<<<nb * 512, 256, 0, stream>>>(ws + doff[0], idx, bo);
  }
  edge1_k<<<2048, 64, 0, stream>>>(points, idx, w1, s1, b1, w2, s2, b2, x1t, x1c);

  // ---- kNN 2 (C=64 on x1c) ----
  xnorm_k<64><<<128, 256, 0, stream>>>(x1c, xxb);
  for (int bo = 0; bo < 16; bo += NB) {
    const int nb = (16 - bo < NB) ? (16 - bo) : NB;
    dist_k<64><<<dim3(16, 16, nb), 256, 0, stream>>>(x1c, xxb, ws + doff[1], bo);
    select_k<<<nb * 512, 256, 0, stream>>>(ws + doff[1], idx, bo);
  }
  edge2_k<<<2048, 64, 0, stream>>>(x1t, idx, w3, s3, b3, w4, s4, b4, x2t, x2c);

  // ---- kNN 3 (C=64 on x2c) ----
  xnorm_k<64><<<128, 256, 0, stream>>>(x2c, xxb);
  for (int bo = 0; bo < 16; bo += NB) {
    const int nb = (16 - bo < NB) ? (16 - bo) : NB;
    dist_k<64><<<dim3(16, 16, nb), 256, 0, stream>>>(x2c, xxb, ws + doff[2], bo);
    select_k<<<nb * 512, 256, 0, stream>>>(ws + doff[2], idx, bo);
  }
  edge3_k<<<2048, 64, 0, stream>>>(x2t, idx, w5, s5, b5, x3c);

  gemm_k<1><<<dim3(16, 16, 16), 256, 0, stream>>>(w6, 192, 0, tabX, 192, s6, b6, nullptr, gpart, 1024);
  gfin_k<<<64, 256, 0, stream>>>(gpart, g);
  tvec_k<<<16, 256, 0, stream>>>(cls, wc, sc, bc, g, wf1, tvec);
  gemm_k<0><<<dim3(16, 4, 16), 256, 0, stream>>>(wf1, 1280, 1088, tabX, 192, sf1, bf1, tvec, f1c, 256);
  gemm_k<0><<<dim3(16, 4, 16), 256, 0, stream>>>(wf2, 256, 0, tabF1, 256, sf2, bf2, nullptr, f2c, 256);
  gemm_k<2><<<dim3(16, 2, 16), 256, 0, stream>>>(wf3, 256, 0, tabF2, 256, sf3, bf3, nullptr, f3t, 128);
  logits_k<<<8192, 256, 0, stream>>>(f3t, wf4, out);
}

// Round 3
// 1930.310 us; speedup vs baseline: 2.5471x; 1.2062x over previous
//
#include <hip/hip_runtime.h>

constexpr int PTS = 2048;   // points per batch
constexpr int KK  = 20;     // knn

static __device__ __forceinline__ float lrelu(float x) { return x >= 0.f ? x : 0.2f * x; }
static __device__ __forceinline__ float rl(float v, int l) {
  return __int_as_float(__builtin_amdgcn_readlane(__float_as_int(v), l));
}
static __device__ __forceinline__ void argmax64(float& v, int& m) {
#pragma unroll
  for (int mask = 1; mask < 64; mask <<= 1) {
    float ov = __shfl_xor(v, mask, 64);
    int om = __shfl_xor(m, mask, 64);
    if (ov > v || (ov == v && om < m)) { v = ov; m = om; }
  }
}

// ---------------- xx[b][m] = sum_c x[c][m]^2 ----------------
template <int C>
__global__ __launch_bounds__(256) void xnorm_k(const float* __restrict__ x, float* __restrict__ xx) {
  const int i = blockIdx.x * 256 + threadIdx.x;  // b*2048 + m
  const int b = i >> 11, m = i & 2047;
  float s = 0.f;
#pragma unroll
  for (int c = 0; c < C; ++c) {
    const float v = x[((long long)b * C + c) * PTS + m];
    s = fmaf(v, v, s);
  }
  xx[i] = s;
}

// ---------------- dist GEMM: D[bl][n][m] = 2*sum_c x[c][n]x[c][m] - xx[m] ----------------
template <int C>
__global__ __launch_bounds__(256) void dist_k(const float* __restrict__ x, const float* __restrict__ xx,
                                              float* __restrict__ D, int bo) {
  constexpr int CP = (C == 3) ? 4 : 32;
  __shared__ float xn[CP * 132];
  __shared__ float xm[CP * 132];
  const int tid = threadIdx.x;
  const int mt = blockIdx.x, nt = blockIdx.y, bl = blockIdx.z;
  const int b = bo + bl;
  const int n0 = nt * 128, m0 = mt * 128;
  const int og = tid & 15, ng = tid >> 4;
  float acc[8][8] = {};
  for (int cc = 0; cc < C; cc += CP) {
    __syncthreads();
    for (int q = tid; q < CP * 32; q += 256) {
      const int c = q >> 5, n4 = (q & 31) << 2;
      float4 vn = {0.f, 0.f, 0.f, 0.f}, vm = {0.f, 0.f, 0.f, 0.f};
      if (cc + c < C) {
        vn = *(const float4*)&x[((long long)b * C + cc + c) * PTS + n0 + n4];
        vm = *(const float4*)&x[((long long)b * C + cc + c) * PTS + m0 + n4];
      }
      *(float4*)&xn[c * 132 + n4] = vn;
      *(float4*)&xm[c * 132 + n4] = vm;
    }
    __syncthreads();
#pragma unroll
    for (int c = 0; c < CP; ++c) {
      const float4 a0 = *(const float4*)&xn[c * 132 + ng * 8];
      const float4 a1 = *(const float4*)&xn[c * 132 + ng * 8 + 4];
      const float4 b0 = *(const float4*)&xm[c * 132 + og * 8];
      const float4 b1 = *(const float4*)&xm[c * 132 + og * 8 + 4];
      const float na[8] = {a0.x, a0.y, a0.z, a0.w, a1.x, a1.y, a1.z, a1.w};
      const float ma[8] = {b0.x, b0.y, b0.z, b0.w, b1.x, b1.y, b1.z, b1.w};
#pragma unroll
      for (int i = 0; i < 8; ++i)
#pragma unroll
        for (int j = 0; j < 8; ++j) acc[i][j] = fmaf(na[i], ma[j], acc[i][j]);
    }
  }
  const float4 xx0 = *(const float4*)&xx[(long long)b * PTS + m0 + og * 8];
  const float4 xx1 = *(const float4*)&xx[(long long)b * PTS + m0 + og * 8 + 4];
  const float xa[8] = {xx0.x, xx0.y, xx0.z, xx0.w, xx1.x, xx1.y, xx1.z, xx1.w};
#pragma unroll
  for (int i = 0; i < 8; ++i) {
    float r[8];
#pragma unroll
    for (int j = 0; j < 8; ++j) r[j] = 2.f * acc[i][j] - xa[j];
    float* op = D + ((long long)bl * PTS + n0 + ng * 8 + i) * PTS + m0 + og * 8;
    float4 v0 = {r[0], r[1], r[2], r[3]};
    float4 v1 = {r[4], r[5], r[6], r[7]};
    *(float4*)op = v0;
    *(float4*)(op + 4) = v1;
  }
}

// ---------------- top-20 selection: 1 wave per point, 4 points/block ----------------
__global__ __launch_bounds__(256) void select_k(const float* __restrict__ D, int* __restrict__ idxout, int bo) {
  __shared__ float sh[4 * 2112];
  const int tid = threadIdx.x, lane = tid & 63, wid = tid >> 6;
  const long long pn = (long long)blockIdx.x * 4 + wid;  // chunk-local point id
  const int bl = (int)(pn >> 11);
  const int n = (int)(pn & 2047);
  const int b = bo + bl;
  float* dp = sh + wid * 2112;
  const float* row = D + pn * PTS;
#pragma unroll
  for (int q = 0; q < 8; ++q) {
    const int m = q * 256 + lane * 4;
    const float4 v = *(const float4*)&row[m];
    dp[((m + 0) & 63) * 33 + ((m + 0) >> 6)] = v.x;
    dp[((m + 1) & 63) * 33 + ((m + 1) >> 6)] = v.y;
    dp[((m + 2) & 63) * 33 + ((m + 2) >> 6)] = v.z;
    dp[((m + 3) & 63) * 33 + ((m + 3) >> 6)] = v.w;
  }
  asm volatile("s_waitcnt lgkmcnt(0)" ::: "memory");
  float bv = -3.4e38f; int bm = 1 << 29;
#pragma unroll 4
  for (int j = 0; j < 32; ++j) {
    float v = dp[lane * 33 + j];
    if (v > bv) { bv = v; bm = lane + (j << 6); }  // ascending m: strict > keeps lowest idx
  }
  int keep = 0;
  for (int r = 0; r < KK; ++r) {
    float cv = bv; int cm = bm;
    argmax64(cv, cm);
    if (lane == r) keep = cm;
    const int sm = cm & 63;
    if (lane == 0) dp[sm * 33 + (cm >> 6)] = -3.4e38f;  // persistent invalidation
    asm volatile("s_waitcnt lgkmcnt(0)" ::: "memory");
    const int jj = lane & 31;  // all-lane rescan of seg sm
    float v2 = dp[sm * 33 + jj];
    int m2 = sm + (jj << 6);
    if (m2 == cm) v2 = -3.4e38f;
    argmax64(v2, m2);
    if (lane == sm) { bv = v2; bm = m2; }
  }
  if (lane < KK) idxout[((long long)b * PTS + n) * KK + lane] = keep;
}

// ---------------- prep: combined PQ weights for edge2/edge3 ----------------
// wc[o][c] (o<64) = w[o][c] (Wa); wc[o][c] (o>=64) = w[o-64][64+c]-w[o-64][c] (Wb-Wa)
__global__ __launch_bounds__(256) void prep_k(
    const float* __restrict__ w3, const float* __restrict__ s3, const float* __restrict__ b3,
    const float* __restrict__ w5, const float* __restrict__ s5, const float* __restrict__ b5,
    float* __restrict__ wc3, float* __restrict__ sc3, float* __restrict__ bc3,
    float* __restrict__ wc5, float* __restrict__ sc5, float* __restrict__ bc5) {
  const int i = blockIdx.x * 256 + threadIdx.x;  // 16384
  const int half = i >> 13;
  const int r = i & 8191;
  const float* w = half ? w5 : w3;
  float* wc = half ? wc5 : wc3;
  const int o = r >> 6, c = r & 63;
  wc[r] = (o < 64) ? w[o * 128 + c] : (w[(o - 64) * 128 + 64 + c] - w[(o - 64) * 128 + c]);
  if (r < 128) {
    const float* s = half ? s5 : s3;
    const float* bb = half ? b5 : b3;
    float* sc = half ? sc5 : sc3;
    float* bc = half ? bc5 : bc3;
    sc[r] = s[r & 63];
    bc[r] = (r < 64) ? 0.f : bb[r - 64];
  }
}

// ---------------- PQ for edge1 (from raw points, w1 is 64x6) ----------------
__global__ __launch_bounds__(256) void pq1_k(const float* __restrict__ pts,
    const float* __restrict__ w1, const float* __restrict__ s1, const float* __restrict__ b1,
    float* __restrict__ PQ) {
  const int i = blockIdx.x * 256 + threadIdx.x;  // 16*2048*64
  const int o = i & 63;
  const int bn = i >> 6;           // b*2048+n
  const int b = bn >> 11, n = bn & 2047;
  const float* pb = pts + (long long)b * 3 * PTS;
  const float x = pb[n], y = pb[PTS + n], z = pb[2 * PTS + n];
  const float s = s1[o];
  const float wa0 = w1[o * 6], wa1 = w1[o * 6 + 1], wa2 = w1[o * 6 + 2];
  const float wb0 = w1[o * 6 + 3], wb1 = w1[o * 6 + 4], wb2 = w1[o * 6 + 5];
  PQ[(long long)bn * 128 + o] = s * (wa0 * x + wa1 * y + wa2 * z);
  PQ[(long long)bn * 128 + 64 + o] =
      fmaf(s, (wb0 - wa0) * x + (wb1 - wa1) * y + (wb2 - wa2) * z, b1[o]);
}

// ---------------- EdgeConv from PQ: y1=lrelu(P[m]+Q[n]); optional conv2; max over k ----------------
template <int CONV2>
__global__ __launch_bounds__(256) void edgepq_k(
    const float* __restrict__ PQ, const int* __restrict__ idxb,
    const float* __restrict__ w2, const float* __restrict__ s2v, const float* __restrict__ b2v,
    float* __restrict__ outC) {
  const int tid = threadIdx.x, lane = tid & 63, wid = tid >> 6;
  const int g = blockIdx.x;
  const int b = g >> 6;                           // 64 blocks per batch
  const int n0 = ((g & 63) << 5) + (wid << 3);    // 32 pts/block, 8 per wave
  float w2r[64];
  float s2o = 0.f, b2o = 0.f;
  if (CONV2) {
#pragma unroll
    for (int k = 0; k < 16; ++k) {
      const float4 v = *(const float4*)&w2[lane * 64 + 4 * k];
      w2r[4 * k] = v.x; w2r[4 * k + 1] = v.y; w2r[4 * k + 2] = v.z; w2r[4 * k + 3] = v.w;
    }
    s2o = s2v[lane]; b2o = b2v[lane];
  }
  const float* Pb = PQ + (long long)b * PTS * 128;
  for (int pt = 0; pt < 8; ++pt) {
    const int n = n0 + pt;
    const float qv = Pb[n * 128 + 64 + lane];
    const int* ir = idxb + ((long long)b * PTS + n) * KK;
    float gm = -3.4e38f;
    int mn = ir[0];
    float pvn = Pb[mn * 128 + lane];
#pragma unroll 2
    for (int j = 0; j < KK; ++j) {
      const float pv = pvn;
      if (j < KK - 1) {
        const int m2 = ir[j + 1];
        pvn = Pb[m2 * 128 + lane];
      }
      const float y1 = lrelu(pv + qv);
      if (CONV2) {
        float d0 = 0.f, d1 = 0.f;
#pragma unroll
        for (int c = 0; c < 64; c += 2) {
          d0 = fmaf(w2r[c], rl(y1, c), d0);
          d1 = fmaf(w2r[c + 1], rl(y1, c + 1), d1);
        }
        gm = fmaxf(gm, lrelu(fmaf(s2o, d0 + d1, b2o)));
      } else {
        gm = fmaxf(gm, y1);
      }
    }
    outC[((long long)b * 64 + lane) * PTS + n] = gm;
  }
}

// ---------------- generic f32 GEMM: W[O,C] * X[C,PTS] ----------------
// MODE 0: affine+lrelu, store [b][O][PTS] (+optional per-(b,o) pre-bias tadd)
// MODE 1: affine+lrelu, max over n -> gpart
// MODE 2: affine+lrelu, store [b][PTS][O]
// MODE 3: affine only (bv nullable), store [b][PTS][O]
struct SrcTab { const float* p[4]; long long bs[4]; };

template <int MODE>
__global__ __launch_bounds__(256) void gemm_k(
    const float* __restrict__ W, int wstride, int c0, SrcTab tab, int C,
    const float* __restrict__ sv, const float* __restrict__ bv, const float* __restrict__ tadd,
    float* __restrict__ out, int O) {
  __shared__ float wT[32 * 68];   // [c][o]
  __shared__ float xT[32 * 132];  // [c][n]
  const int tid = threadIdx.x;
  const int nt = blockIdx.x, ot = blockIdx.y, b = blockIdx.z;
  const int n0 = nt * 128, o0 = ot * 64;
  const int og = tid & 15, ng = tid >> 4;
  float acc[4][8] = {};
  for (int cc = 0; cc < C; cc += 32) {
    __syncthreads();
    for (int q = tid; q < 512; q += 256) {
      const int row = q >> 3, c4 = (q & 7) << 2;
      const float4 v = *(const float4*)&W[(long long)(o0 + row) * wstride + c0 + cc + c4];
      wT[(c4 + 0) * 68 + row] = v.x;
      wT[(c4 + 1) * 68 + row] = v.y;
      wT[(c4 + 2) * 68 + row] = v.z;
      wT[(c4 + 3) * 68 + row] = v.w;
    }
    for (int q = tid; q < 1024; q += 256) {
      const int c = q >> 5, n4 = (q & 31) << 2;
      const int cg = cc + c;
      const float4 v = *(const float4*)(tab.p[cg >> 6] + tab.bs[cg >> 6] * b + (long long)(cg & 63) * PTS + n0 + n4);
      *(float4*)&xT[c * 132 + n4] = v;
    }
    __syncthreads();
#pragma unroll 8
    for (int c = 0; c < 32; ++c) {
      const float4 av = *(const float4*)&wT[c * 68 + og * 4];
      const float4 x0 = *(const float4*)&xT[c * 132 + ng * 8];
      const float4 x1 = *(const float4*)&xT[c * 132 + ng * 8 + 4];
      const float aa[4] = {av.x, av.y, av.z, av.w};
      const float xx[8] = {x0.x, x0.y, x0.z, x0.w, x1.x, x1.y, x1.z, x1.w};
#pragma unroll
      for (int oi = 0; oi < 4; ++oi)
#pragma unroll
        for (int nj = 0; nj < 8; ++nj) acc[oi][nj] = fmaf(aa[oi], xx[nj], acc[oi][nj]);
    }
  }
  if (MODE == 1) {
    __syncthreads();
    float* red = xT;
#pragma unroll
    for (int oi = 0; oi < 4; ++oi) {
      const int o = o0 + og * 4 + oi;
      const float s = sv[o], bb = bv[o];
      float pm = -3.4e38f;
#pragma unroll
      for (int nj = 0; nj < 8; ++nj) pm = fmaxf(pm, lrelu(fmaf(s, acc[oi][nj], bb)));
      red[(og * 4 + oi) * 16 + ng] = pm;
    }
    __syncthreads();
    if (tid < 64) {
      float m = red[tid * 16];
#pragma unroll
      for (int k = 1; k < 16; ++k) m = fmaxf(m, red[tid * 16 + k]);
      out[((long long)b * 16 + nt) * 1024 + o0 + tid] = m;
    }
  } else if (MODE == 0) {
#pragma unroll
    for (int oi = 0; oi < 4; ++oi) {
      const int o = o0 + og * 4 + oi;
      const float s = sv[o], bb = bv[o];
      const float tv = (tadd != nullptr) ? tadd[(long long)b * O + o] : 0.f;
      float r[8];
#pragma unroll
      for (int nj = 0; nj < 8; ++nj) r[nj] = lrelu(fmaf(s, acc[oi][nj] + tv, bb));
      float4 v0 = {r[0], r[1], r[2], r[3]};
      float4 v1 = {r[4], r[5], r[6], r[7]};
      float* op = out + ((long long)b * O + o) * PTS + n0 + ng * 8;
      *(float4*)op = v0;
      *(float4*)(op + 4) = v1;
    }
  } else if (MODE == 2) {
    float so[4], bo[4];
#pragma unroll
    for (int oi = 0; oi < 4; ++oi) { so[oi] = sv[o0 + og * 4 + oi]; bo[oi] = bv[o0 + og * 4 + oi]; }
#pragma unroll
    for (int nj = 0; nj < 8; ++nj) {
      const int n = n0 + ng * 8 + nj;
      float4 v;
      v.x = lrelu(fmaf(so[0], acc[0][nj], bo[0]));
      v.y = lrelu(fmaf(so[1], acc[1][nj], bo[1]));
      v.z = lrelu(fmaf(so[2], acc[2][nj], bo[2]));
      v.w = lrelu(fmaf(so[3], acc[3][nj], bo[3]));
      *(float4*)&out[((long long)b * PTS + n) * O + o0 + og * 4] = v;
    }
  } else {  // MODE 3: affine only, bv nullable
    float so[4], bo[4];
#pragma unroll
    for (int oi = 0; oi < 4; ++oi) {
      so[oi] = sv[o0 + og * 4 + oi];
      bo[oi] = (bv != nullptr) ? bv[o0 + og * 4 + oi] : 0.f;
    }
#pragma unroll
    for (int nj = 0; nj < 8; ++nj) {
      const int n = n0 + ng * 8 + nj;
      float4 v;
      v.x = fmaf(so[0], acc[0][nj], bo[0]);
      v.y = fmaf(so[1], acc[1][nj], bo[1]);
      v.z = fmaf(so[2], acc[2][nj], bo[2]);
      v.w = fmaf(so[3], acc[3][nj], bo[3]);
      *(float4*)&out[((long long)b * PTS + n) * O + o0 + og * 4] = v;
    }
  }
}

// ---------------- finalize global max g[b][1024] ----------------
__global__ __launch_bounds__(256) void gfin_k(const float* __restrict__ gp, float* __restrict__ g) {
  const int i = blockIdx.x * 256 + threadIdx.x;
  const int b = i >> 10, o = i & 1023;
  float m = -3.4e38f;
#pragma unroll 4
  for (int t = 0; t < 16; ++t) m = fmaxf(m, gp[((long long)b * 16 + t) * 1024 + o]);
  g[i] = m;
}

// ---------------- tvec[b][256] = Wf1[:, :1024] * g + Wf1[:, 1024:1088] * cv ----------------
__global__ __launch_bounds__(256) void tvec_k(
    const float* __restrict__ cls, const float* __restrict__ wc, const float* __restrict__ sc,
    const float* __restrict__ bc, const float* __restrict__ g, const float* __restrict__ wf1,
    float* __restrict__ tvec) {
  __shared__ float gs[1024];
  __shared__ float cvs[64];
  const int b = blockIdx.x, tid = threadIdx.x;
  for (int q = tid; q < 1024; q += 256) gs[q] = g[b * 1024 + q];
  if (tid < 64) {
    float a = 0.f;
#pragma unroll
    for (int j = 0; j < 16; ++j) a = fmaf(wc[tid * 16 + j], cls[b * 16 + j], a);
    cvs[tid] = lrelu(fmaf(sc[tid], a, bc[tid]));
  }
  __syncthreads();
  const float* wr = wf1 + (long long)tid * 1280;
  float a0 = 0.f, a1 = 0.f;
  for (int c = 0; c < 1024; c += 4) {
    const float4 w = *(const float4*)&wr[c];
    const float4 gv = *(const float4*)&gs[c];
    a0 = fmaf(w.x, gv.x, a0); a1 = fmaf(w.y, gv.y, a1);
    a0 = fmaf(w.z, gv.z, a0); a1 = fmaf(w.w, gv.w, a1);
  }
#pragma unroll
  for (int c = 0; c < 64; c += 4) {
    const float4 w = *(const float4*)&wr[1024 + c];
    const float4 cv = *(const float4*)&cvs[c];
    a0 = fmaf(w.x, cv.x, a0); a1 = fmaf(w.y, cv.y, a1);
    a0 = fmaf(w.z, cv.z, a0); a1 = fmaf(w.w, cv.w, a1);
  }
  tvec[b * 256 + tid] = a0 + a1;
}

// ---------------- logits (50x128) + log_softmax + [B][N][50] store ----------------
__global__ __launch_bounds__(256) void logits_k(const float* __restrict__ f3t, const float* __restrict__ wf4,
                                                float* __restrict__ out) {
  __shared__ float wT[6464];   // wT[c*50 + o]
  const int tid = threadIdx.x, lane = tid & 63, wv = tid >> 6;
  for (int q = tid; q < 6400; q += 256) {
    const int o = q >> 7, c = q & 127;
    wT[c * 50 + o] = wf4[q];
  }
  __syncthreads();
  const long long pn = (long long)blockIdx.x * 4 + wv;
  const float lo = f3t[pn * 128 + lane], hi = f3t[pn * 128 + 64 + lane];
  float a0 = 0.f, a1 = 0.f;
#pragma unroll
  for (int c = 0; c < 64; c += 2) {
    a0 = fmaf(wT[c * 50 + lane], rl(lo, c), a0);
    a1 = fmaf(wT[(c + 1) * 50 + lane], rl(lo, c + 1), a1);
  }
#pragma unroll
  for (int c = 0; c < 64; c += 2) {
    a0 = fmaf(wT[(64 + c) * 50 + lane], rl(hi, c), a0);
    a1 = fmaf(wT[(65 + c) * 50 + lane], rl(hi, c + 1), a1);
  }
  const float logit = (lane < 50) ? (a0 + a1) : -3.4e38f;
  float M = logit;
#pragma unroll
  for (int mask = 1; mask < 64; mask <<= 1) M = fmaxf(M, __shfl_xor(M, mask, 64));
  const float ex = (lane < 50) ? __expf(logit - M) : 0.f;
  float S = ex;
#pragma unroll
  for (int mask = 1; mask < 64; mask <<= 1) S += __shfl_xor(S, mask, 64);
  if (lane < 50) out[pn * 50 + lane] = logit - M - __logf(S);
}

extern "C" void kernel_launch(void* const* d_in, const int* in_sizes, int n_in,
                              void* d_out, int out_size, void* d_ws, size_t ws_size,
                              hipStream_t stream) {
  (void)in_sizes; (void)n_in; (void)out_size;
  const float* points = (const float*)d_in[0];
  const float* cls = (const float*)d_in[1];
  const float* w1 = (const float*)d_in[2];
  const float* s1 = (const float*)d_in[3];
  const float* b1 = (const float*)d_in[4];
  const float* w2 = (const float*)d_in[5];
  const float* s2 = (const float*)d_in[6];
  const float* b2 = (const float*)d_in[7];
  const float* w3 = (const float*)d_in[8];
  const float* s3 = (const float*)d_in[9];
  const float* b3 = (const float*)d_in[10];
  const float* w4 = (const float*)d_in[11];
  const float* s4 = (const float*)d_in[12];
  const float* b4 = (const float*)d_in[13];
  const float* w5 = (const float*)d_in[14];
  const float* s5 = (const float*)d_in[15];
  const float* b5 = (const float*)d_in[16];
  const float* w6 = (const float*)d_in[17];
  const float* s6 = (const float*)d_in[18];
  const float* b6 = (const float*)d_in[19];
  const float* wc = (const float*)d_in[20];
  const float* sc = (const float*)d_in[21];
  const float* bc = (const float*)d_in[22];
  const float* wf1 = (const float*)d_in[23];
  const float* sf1 = (const float*)d_in[24];
  const float* bf1 = (const float*)d_in[25];
  const float* wf2 = (const float*)d_in[26];
  const float* sf2 = (const float*)d_in[27];
  const float* bf2 = (const float*)d_in[28];
  const float* wf3 = (const float*)d_in[29];
  const float* sf3 = (const float*)d_in[30];
  const float* bf3 = (const float*)d_in[31];
  const float* wf4 = (const float*)d_in[32];
  float* out = (float*)d_out;
  float* ws = (float*)d_ws;

  // workspace layout (floats):
  // x1c@0  x2c@2097152  x3c@4194304  f1c@8388608(..16777216)
  // f2c@0 (aliases x*c, dead by then)  f3t/PQ@8388608 (time-share f1c region)
  // aux block @16777216+
  float* x1c = ws;
  float* x2c = ws + 2097152LL;
  float* x3c = ws + 4194304LL;
  float* f1c = ws + 8388608LL;
  float* f2c = ws;
  float* f3t = ws + 8388608LL;
  float* PQ  = ws + 8388608LL;
  int*   idx = (int*)(ws + 16777216LL);
  float* xxb = ws + 17432576LL;
  float* gpart = ws + 17465344LL;
  float* g = ws + 17727488LL;
  float* tvec = ws + 17743872LL;
  float* wc3 = ws + 17747968LL;
  float* sc3 = ws + 17756160LL;
  float* bc3 = ws + 17756288LL;
  float* wc5 = ws + 17756416LL;
  float* sc5 = ws + 17764608LL;
  float* bc5 = ws + 17764736LL;
  const long long staticEnd = 17764864LL;

  // D scratch: chunked by available ws. Fallback NB=2 time-shares the f1c region.
  const long long DBATCH = (long long)PTS * PTS;  // 4194304 floats
  int NB; float* Dbuf;
  if (ws_size >= (size_t)(staticEnd + 16 * DBATCH) * 4) { NB = 16; Dbuf = ws + staticEnd; }
  else if (ws_size >= (size_t)(staticEnd + 4 * DBATCH) * 4) { NB = 4; Dbuf = ws + staticEnd; }
  else { NB = 2; Dbuf = ws + 8388608LL; }

  SrcTab tabX{{x1c, x2c, x3c, nullptr}, {64LL * PTS, 64LL * PTS, 64LL * PTS, 0}};
  SrcTab tabX1{{x1c, nullptr, nullptr, nullptr}, {64LL * PTS, 0, 0, 0}};
  SrcTab tabX2{{x2c, nullptr, nullptr, nullptr}, {64LL * PTS, 0, 0, 0}};
  SrcTab tabF1{{f1c, f1c + 64 * PTS, f1c + 128 * PTS, f1c + 192 * PTS},
               {256LL * PTS, 256LL * PTS, 256LL * PTS, 256LL * PTS}};
  SrcTab tabF2{{f2c, f2c + 64 * PTS, f2c + 128 * PTS, f2c + 192 * PTS},
               {256LL * PTS, 256LL * PTS, 256LL * PTS, 256LL * PTS}};

  prep_k<<<64, 256, 0, stream>>>(w3, s3, b3, w5, s5, b5, wc3, sc3, bc3, wc5, sc5, bc5);

  // ---- kNN 1 (C=3 on points) + edge1 ----
  xnorm_k<3><<<128, 256, 0, stream>>>(points, xxb);
  for (int bo = 0; bo < 16; bo += NB) {
    const int nb = (16 - bo < NB) ? (16 - bo) : NB;
    dist_k<3><<<dim3(16, 16, nb), 256, 0, stream>>>(points, xxb, Dbuf, bo);
    select_k<<<nb * 512, 256, 0, stream>>>(Dbuf, idx, bo);
  }
  pq1_k<<<8192, 256, 0, stream>>>(points, w1, s1, b1, PQ);
  edgepq_k<1><<<1024, 256, 0, stream>>>(PQ, idx, w2, s2, b2, x1c);

  // ---- kNN 2 (C=64 on x1c) + edge2 ----
  xnorm_k<64><<<128, 256, 0, stream>>>(x1c, xxb);
  for (int bo = 0; bo < 16; bo += NB) {
    const int nb = (16 - bo < NB) ? (16 - bo) : NB;
    dist_k<64><<<dim3(16, 16, nb), 256, 0, stream>>>(x1c, xxb, Dbuf, bo);
    select_k<<<nb * 512, 256, 0, stream>>>(Dbuf, idx, bo);
  }
  gemm_k<3><<<dim3(16, 2, 16), 256, 0, stream>>>(wc3, 64, 0, tabX1, 64, sc3, bc3, nullptr, PQ, 128);
  edgepq_k<1><<<1024, 256, 0, stream>>>(PQ, idx, w4, s4, b4, x2c);

  // ---- kNN 3 (C=64 on x2c) + edge3 ----
  xnorm_k<64><<<128, 256, 0, stream>>>(x2c, xxb);
  for (int bo = 0; bo < 16; bo += NB) {
    const int nb = (16 - bo < NB) ? (16 - bo) : NB;
    dist_k<64><<<dim3(16, 16, nb), 256, 0, stream>>>(x2c, xxb, Dbuf, bo);
    select_k<<<nb * 512, 256, 0, stream>>>(Dbuf, idx, bo);
  }
  gemm_k<3><<<dim3(16, 2, 16), 256, 0, stream>>>(wc5, 64, 0, tabX2, 64, sc5, bc5, nullptr, PQ, 128);
  edgepq_k<0><<<1024, 256, 0, stream>>>(PQ, idx, nullptr, nullptr, nullptr, x3c);

  // ---- head ----
  gemm_k<1><<<dim3(16, 16, 16), 256, 0, stream>>>(w6, 192, 0, tabX, 192, s6, b6, nullptr, gpart, 1024);
  gfin_k<<<64, 256, 0, stream>>>(gpart, g);
  tvec_k<<<16, 256, 0, stream>>>(cls, wc, sc, bc, g, wf1, tvec);
  gemm_k<0><<<dim3(16, 4, 16), 256, 0, stream>>>(wf1, 1280, 1088, tabX, 192, sf1, bf1, tvec, f1c, 256);
  gemm_k<0><<<dim3(16, 4, 16), 256, 0, stream>>>(wf2, 256, 0, tabF1, 256, sf2, bf2, nullptr, f2c, 256);
  gemm_k<2><<<dim3(16, 2, 16), 256, 0, stream>>>(wf3, 256, 0, tabF2, 256, sf3, bf3, nullptr, f3t, 128);
  logits_k<<<8192, 256, 0, stream>>>(f3t, wf4, out);
}

// Round 5
// 1564.135 us; speedup vs baseline: 3.1434x; 1.2341x over previous
//
#include <hip/hip_runtime.h>

constexpr int PTS = 2048;   // points per batch
constexpr int KK  = 20;     // knn

typedef __attribute__((ext_vector_type(8))) short bf8;
typedef __attribute__((ext_vector_type(4))) float f32x4;

static __device__ __forceinline__ float lrelu(float x) { return fmaxf(x, 0.2f * x); }
static __device__ __forceinline__ float rl(float v, int l) {
  return __int_as_float(__builtin_amdgcn_readlane(__float_as_int(v), l));
}
static __device__ __forceinline__ unsigned cvt2(float lo, float hi) {
  unsigned r;
  asm("v_cvt_pk_bf16_f32 %0, %1, %2" : "=v"(r) : "v"(lo), "v"(hi));
  return r;
}
// residual after bf16-hi extraction: packs bf16(a - hi(a)), bf16(b - hi(b))
static __device__ __forceinline__ unsigned cvt2lo(float a, float b, unsigned h) {
  return cvt2(a - __uint_as_float(h << 16), b - __uint_as_float(h & 0xffff0000u));
}
static __device__ __forceinline__ unsigned short rne_bf16(float v) {
  unsigned u = __float_as_uint(v);
  return (unsigned short)((u + 0x7fffu + ((u >> 16) & 1u)) >> 16);
}
static __device__ __forceinline__ float bf2f(unsigned short u) {
  return __uint_as_float(((unsigned)u) << 16);
}
static __device__ __forceinline__ int swz(int row, int slot) {
  return slot ^ (row & 3) ^ ((row >> 2) & 3);   // 16B-slot swizzle, conflict-free
}
static __device__ __forceinline__ void argmax64(float& v, int& m) {
#pragma unroll
  for (int mask = 1; mask < 64; mask <<= 1) {
    float ov = __shfl_xor(v, mask, 64);
    int om = __shfl_xor(m, mask, 64);
    if (ov > v || (ov == v && om < m)) { v = ov; m = om; }
  }
}

// ---------------- xx[b][m] = sum_c x[c][m]^2 ----------------
template <int C>
__global__ __launch_bounds__(256) void xnorm_k(const float* __restrict__ x, float* __restrict__ xx) {
  const int i = blockIdx.x * 256 + threadIdx.x;
  const int b = i >> 11, m = i & 2047;
  float s = 0.f;
#pragma unroll
  for (int c = 0; c < C; ++c) {
    const float v = x[((long long)b * C + c) * PTS + m];
    s = fmaf(v, v, s);
  }
  xx[i] = s;
}

// ---------------- dist GEMM (f32, topology-critical): D[bl][n][m] = 2*<x_n,x_m> - xx[m] ----------------
template <int C>
__global__ __launch_bounds__(256) void dist_k(const float* __restrict__ x, const float* __restrict__ xx,
                                              float* __restrict__ D, int bo) {
  constexpr int CP = (C == 3) ? 4 : 32;
  __shared__ float xn[CP * 132];
  __shared__ float xm[CP * 132];
  const int tid = threadIdx.x;
  const int mt = blockIdx.x, nt = blockIdx.y, bl = blockIdx.z;
  const int b = bo + bl;
  const int n0 = nt * 128, m0 = mt * 128;
  const int og = tid & 15, ng = tid >> 4;
  float acc[8][8] = {};
  for (int cc = 0; cc < C; cc += CP) {
    __syncthreads();
    for (int q = tid; q < CP * 32; q += 256) {
      const int c = q >> 5, n4 = (q & 31) << 2;
      float4 vn = {0.f, 0.f, 0.f, 0.f}, vm = {0.f, 0.f, 0.f, 0.f};
      if (cc + c < C) {
        vn = *(const float4*)&x[((long long)b * C + cc + c) * PTS + n0 + n4];
        vm = *(const float4*)&x[((long long)b * C + cc + c) * PTS + m0 + n4];
      }
      *(float4*)&xn[c * 132 + n4] = vn;
      *(float4*)&xm[c * 132 + n4] = vm;
    }
    __syncthreads();
#pragma unroll
    for (int c = 0; c < CP; ++c) {
      const float4 a0 = *(const float4*)&xn[c * 132 + ng * 8];
      const float4 a1 = *(const float4*)&xn[c * 132 + ng * 8 + 4];
      const float4 b0 = *(const float4*)&xm[c * 132 + og * 8];
      const float4 b1 = *(const float4*)&xm[c * 132 + og * 8 + 4];
      const float na[8] = {a0.x, a0.y, a0.z, a0.w, a1.x, a1.y, a1.z, a1.w};
      const float ma[8] = {b0.x, b0.y, b0.z, b0.w, b1.x, b1.y, b1.z, b1.w};
#pragma unroll
      for (int i = 0; i < 8; ++i)
#pragma unroll
        for (int j = 0; j < 8; ++j) acc[i][j] = fmaf(na[i], ma[j], acc[i][j]);
    }
  }
  const float4 xx0 = *(const float4*)&xx[(long long)b * PTS + m0 + og * 8];
  const float4 xx1 = *(const float4*)&xx[(long long)b * PTS + m0 + og * 8 + 4];
  const float xa[8] = {xx0.x, xx0.y, xx0.z, xx0.w, xx1.x, xx1.y, xx1.z, xx1.w};
#pragma unroll
  for (int i = 0; i < 8; ++i) {
    float r[8];
#pragma unroll
    for (int j = 0; j < 8; ++j) r[j] = 2.f * acc[i][j] - xa[j];
    float* op = D + ((long long)bl * PTS + n0 + ng * 8 + i) * PTS + m0 + og * 8;
    float4 v0 = {r[0], r[1], r[2], r[3]};
    float4 v1 = {r[4], r[5], r[6], r[7]};
    *(float4*)op = v0;
    *(float4*)(op + 4) = v1;
  }
}

// ---------------- top-20 selection: 1 wave per point ----------------
__global__ __launch_bounds__(256) void select_k(const float* __restrict__ D, int* __restrict__ idxout, int bo) {
  __shared__ float sh[4 * 2112];
  const int tid = threadIdx.x, lane = tid & 63, wid = tid >> 6;
  const long long pn = (long long)blockIdx.x * 4 + wid;
  const int bl = (int)(pn >> 11);
  const int n = (int)(pn & 2047);
  const int b = bo + bl;
  float* dp = sh + wid * 2112;
  const float* row = D + pn * PTS;
#pragma unroll
  for (int q = 0; q < 8; ++q) {
    const int m = q * 256 + lane * 4;
    const float4 v = *(const float4*)&row[m];
    dp[((m + 0) & 63) * 33 + ((m + 0) >> 6)] = v.x;
    dp[((m + 1) & 63) * 33 + ((m + 1) >> 6)] = v.y;
    dp[((m + 2) & 63) * 33 + ((m + 2) >> 6)] = v.z;
    dp[((m + 3) & 63) * 33 + ((m + 3) >> 6)] = v.w;
  }
  asm volatile("s_waitcnt lgkmcnt(0)" ::: "memory");
  float bv = -3.4e38f; int bm = 1 << 29;
#pragma unroll 4
  for (int j = 0; j < 32; ++j) {
    float v = dp[lane * 33 + j];
    if (v > bv) { bv = v; bm = lane + (j << 6); }
  }
  int keep = 0;
  for (int r = 0; r < KK; ++r) {
    float cv = bv; int cm = bm;
    argmax64(cv, cm);
    if (lane == r) keep = cm;
    const int sm = cm & 63;
    if (lane == 0) dp[sm * 33 + (cm >> 6)] = -3.4e38f;
    asm volatile("s_waitcnt lgkmcnt(0)" ::: "memory");
    const int jj = lane & 31;
    float v2 = dp[sm * 33 + jj];
    int m2 = sm + (jj << 6);
    if (m2 == cm) v2 = -3.4e38f;
    argmax64(v2, m2);
    if (lane == sm) { bv = v2; bm = m2; }
  }
  if (lane < KK) idxout[((long long)b * PTS + n) * KK + lane] = keep;
}

// ---------------- prep: combined PQ weights (f32) for edge2/edge3 ----------------
__global__ __launch_bounds__(256) void prep_k(
    const float* __restrict__ w3, const float* __restrict__ s3, const float* __restrict__ b3,
    const float* __restrict__ w5, const float* __restrict__ s5, const float* __restrict__ b5,
    float* __restrict__ wc3, float* __restrict__ sc3, float* __restrict__ bc3,
    float* __restrict__ wc5, float* __restrict__ sc5, float* __restrict__ bc5) {
  const int i = blockIdx.x * 256 + threadIdx.x;  // 16384
  const int half = i >> 13;
  const int r = i & 8191;
  const float* w = half ? w5 : w3;
  float* wcp = half ? wc5 : wc3;
  const int o = r >> 6, c = r & 63;
  wcp[r] = (o < 64) ? w[o * 128 + c] : (w[(o - 64) * 128 + 64 + c] - w[(o - 64) * 128 + c]);
  if (r < 128) {
    const float* s = half ? s5 : s3;
    const float* bb = half ? b5 : b3;
    float* scp = half ? sc5 : sc3;
    float* bcp = half ? bc5 : bc3;
    scp[r] = s[r & 63];
    bcp[r] = (r < 64) ? 0.f : bb[r - 64];
  }
}

// ---------------- split conv2 weights to bf16 hi/lo ----------------
__global__ __launch_bounds__(256) void wsplit_k(const float* __restrict__ w2, const float* __restrict__ w4,
                                                unsigned short* __restrict__ W2hi, unsigned short* __restrict__ W2lo,
                                                unsigned short* __restrict__ W4hi, unsigned short* __restrict__ W4lo) {
  const int i = blockIdx.x * 256 + threadIdx.x;  // 8192
  const float v = (i < 4096) ? w2[i] : w4[i - 4096];
  const unsigned short h = rne_bf16(v);
  const unsigned short l = rne_bf16(v - bf2f(h));
  if (i < 4096) { W2hi[i] = h; W2lo[i] = l; }
  else { W4hi[i - 4096] = h; W4lo[i - 4096] = l; }
}

// ---------------- PQ for edge1 (f32 out, [b][n][128]: P=0..63, Q=64..127) ----------------
__global__ __launch_bounds__(256) void pq1_k(const float* __restrict__ pts,
    const float* __restrict__ w1, const float* __restrict__ s1, const float* __restrict__ b1,
    float* __restrict__ PQ) {
  const int i = blockIdx.x * 256 + threadIdx.x;  // 16*2048*64
  const int o = i & 63;
  const int bn = i >> 6;
  const int b = bn >> 11, n = bn & 2047;
  const float* pb = pts + (long long)b * 3 * PTS;
  const float x = pb[n], y = pb[PTS + n], z = pb[2 * PTS + n];
  const float s = s1[o];
  const float wa0 = w1[o * 6], wa1 = w1[o * 6 + 1], wa2 = w1[o * 6 + 2];
  const float wb0 = w1[o * 6 + 3], wb1 = w1[o * 6 + 4], wb2 = w1[o * 6 + 5];
  PQ[(long long)bn * 128 + o] = s * (wa0 * x + wa1 * y + wa2 * z);
  PQ[(long long)bn * 128 + 64 + o] =
      fmaf(s, (wb0 - wa0) * x + (wb1 - wa1) * y + (wb2 - wa2) * z, b1[o]);
}

// ---------------- MFMA EdgeConv (split-bf16 3-pass): conv2 as pair-GEMM, max over k ----------------
static __device__ __forceinline__ void mkfrag2(const float4 p0, const float4 p1,
                                               const float4 q0, const float4 q1,
                                               bf8& hi, bf8& lo) {
  const float y[8] = {p0.x + q0.x, p0.y + q0.y, p0.z + q0.z, p0.w + q0.w,
                      p1.x + q1.x, p1.y + q1.y, p1.z + q1.z, p1.w + q1.w};
  union { unsigned u[4]; bf8 v; } rh, rlo;
#pragma unroll
  for (int i = 0; i < 4; ++i) {
    const float a = lrelu(y[2 * i]), b = lrelu(y[2 * i + 1]);
    const unsigned h = cvt2(a, b);
    rh.u[i] = h;
    rlo.u[i] = cvt2lo(a, b, h);
  }
  hi = rh.v; lo = rlo.v;
}

__global__ __launch_bounds__(256) void edgemf_k(
    const float* __restrict__ PQ, const int* __restrict__ idxb,
    const unsigned short* __restrict__ Whi, const unsigned short* __restrict__ Wlo,
    const float* __restrict__ s2v, const float* __restrict__ b2v,
    float* __restrict__ outC) {
  const int lane = threadIdx.x & 63, wid = threadIdx.x >> 6;
  const int g = blockIdx.x;                 // 16b * 256
  const int b = g >> 8;
  const int n0 = (g & 255) * 8 + wid * 2;   // 8 pts/block, 2 per wave
  bf8 wbh[4][2], wbl[4][2];
#pragma unroll
  for (int nf = 0; nf < 4; ++nf)
#pragma unroll
    for (int kt = 0; kt < 2; ++kt) {
      const int off = (16 * nf + (lane & 15)) * 64 + kt * 32 + (lane >> 4) * 8;
      wbh[nf][kt] = *(const bf8*)&Whi[off];
      wbl[nf][kt] = *(const bf8*)&Wlo[off];
    }
  const float* Pb = PQ + (long long)b * PTS * 128;
  f32x4 acc[4][4] = {};
  for (int pt = 0; pt < 2; ++pt) {
    const int n = n0 + pt;
    const int* ir = idxb + ((long long)b * PTS + n) * KK;
    const int co = (lane >> 4) * 8;
    const float4 q0a = *(const float4*)&Pb[n * 128 + 64 + co];
    const float4 q0b = *(const float4*)&Pb[n * 128 + 68 + co];
    const float4 q1a = *(const float4*)&Pb[n * 128 + 96 + co];
    const float4 q1b = *(const float4*)&Pb[n * 128 + 100 + co];
#pragma unroll
    for (int f = 0; f < 2; ++f) {
      const int j = f * 16 + (lane & 15);
      const int m = ir[j < KK ? j : 0];
      const float4 p0a = *(const float4*)&Pb[m * 128 + co];
      const float4 p0b = *(const float4*)&Pb[m * 128 + 4 + co];
      const float4 p1a = *(const float4*)&Pb[m * 128 + 32 + co];
      const float4 p1b = *(const float4*)&Pb[m * 128 + 36 + co];
      bf8 a0h, a0l, a1h, a1l;
      mkfrag2(p0a, p0b, q0a, q0b, a0h, a0l);
      mkfrag2(p1a, p1b, q1a, q1b, a1h, a1l);
      const int mf = pt * 2 + f;
#pragma unroll
      for (int nf = 0; nf < 4; ++nf) {
        acc[mf][nf] = __builtin_amdgcn_mfma_f32_16x16x32_bf16(a0h, wbh[nf][0], acc[mf][nf], 0, 0, 0);
        acc[mf][nf] = __builtin_amdgcn_mfma_f32_16x16x32_bf16(a0l, wbh[nf][0], acc[mf][nf], 0, 0, 0);
        acc[mf][nf] = __builtin_amdgcn_mfma_f32_16x16x32_bf16(a0h, wbl[nf][0], acc[mf][nf], 0, 0, 0);
      }
#pragma unroll
      for (int nf = 0; nf < 4; ++nf) {
        acc[mf][nf] = __builtin_amdgcn_mfma_f32_16x16x32_bf16(a1h, wbh[nf][1], acc[mf][nf], 0, 0, 0);
        acc[mf][nf] = __builtin_amdgcn_mfma_f32_16x16x32_bf16(a1l, wbh[nf][1], acc[mf][nf], 0, 0, 0);
        acc[mf][nf] = __builtin_amdgcn_mfma_f32_16x16x32_bf16(a1h, wbl[nf][1], acc[mf][nf], 0, 0, 0);
      }
    }
  }
#pragma unroll
  for (int nf = 0; nf < 4; ++nf) {
    const int o = 16 * nf + (lane & 15);
    const float so = s2v[o], bo = b2v[o];
#pragma unroll
    for (int pt = 0; pt < 2; ++pt) {
      float v = -3.4e38f;
#pragma unroll
      for (int f = 0; f < 2; ++f) {
        const int mf = pt * 2 + f;
#pragma unroll
        for (int r = 0; r < 4; ++r) v = fmaxf(v, lrelu(fmaf(so, acc[mf][nf][r], bo)));
      }
      v = fmaxf(v, __shfl_xor(v, 16, 64));
      v = fmaxf(v, __shfl_xor(v, 32, 64));
      if ((lane >> 4) == 0) outC[((long long)b * 64 + o) * PTS + n0 + pt] = v;
    }
  }
}

// ---------------- edge3: gather-max of lrelu(P+Q), f32 PQ ----------------
__global__ __launch_bounds__(256) void edge3f_k(const float* __restrict__ PQ,
                                                const int* __restrict__ idxb, float* __restrict__ outC) {
  const int lane = threadIdx.x & 63, wid = threadIdx.x >> 6;
  const int g = blockIdx.x;
  const int b = g >> 6, n0 = ((g & 63) << 5) + (wid << 3);
  const float* Pb = PQ + (long long)b * PTS * 128;
  for (int pt = 0; pt < 8; ++pt) {
    const int n = n0 + pt;
    const float qv = Pb[n * 128 + 64 + lane];
    const int* ir = idxb + ((long long)b * PTS + n) * KK;
    float gm = -3.4e38f;
#pragma unroll 4
    for (int j = 0; j < KK; ++j) {
      const int m = ir[j];
      gm = fmaxf(gm, lrelu(Pb[m * 128 + lane] + qv));
    }
    outC[((long long)b * 64 + lane) * PTS + n] = gm;
  }
}

// ---------------- bf16 MFMA GEMM, optional split-bf16 3-pass ----------------
// MODE 0: affine+lrelu -> [b][O][PTS] (+tadd) | MODE 1: affine+lrelu, max over n -> gpart
// MODE 2: affine+lrelu -> [b][PTS][O] f32     | MODE 3: affine only -> f32 [b][PTS][O]
struct SrcTab { const float* p[4]; long long bs[4]; };

template <int MODE, int SPLIT>
__global__ __launch_bounds__(256) void mfgemm_k(
    const float* __restrict__ W, int wstride, int c0, SrcTab tab, int C,
    const float* __restrict__ sv, const float* __restrict__ bv, const float* __restrict__ tadd,
    float* __restrict__ out, int O) {
  __shared__ __align__(16) short Wl[(1 + SPLIT) * 128 * 32];
  __shared__ __align__(16) short Xl[(1 + SPLIT) * 128 * 32];
  __shared__ float red[2][128];
  const int tid = threadIdx.x, lane = tid & 63, wid = tid >> 6;
  const int nt = blockIdx.x, ot = blockIdx.y, b = blockIdx.z;
  const int n0 = nt * 128, o0 = ot * 128;
  const int wm = wid >> 1, wn = wid & 1;
  f32x4 acc[4][4] = {};
  for (int cc = 0; cc < C; cc += 32) {
    __syncthreads();
    {
      const int o = tid >> 1, hf = tid & 1;
      const float* src = &W[(long long)(o0 + o) * wstride + c0 + cc + hf * 16];
      const float4 v0 = *(const float4*)src;
      const float4 v1 = *(const float4*)(src + 4);
      const float4 v2 = *(const float4*)(src + 8);
      const float4 v3 = *(const float4*)(src + 12);
      uint4 d0, d1;
      d0.x = cvt2(v0.x, v0.y); d0.y = cvt2(v0.z, v0.w);
      d0.z = cvt2(v1.x, v1.y); d0.w = cvt2(v1.z, v1.w);
      d1.x = cvt2(v2.x, v2.y); d1.y = cvt2(v2.z, v2.w);
      d1.z = cvt2(v3.x, v3.y); d1.w = cvt2(v3.z, v3.w);
      *(uint4*)&Wl[o * 32 + swz(o, hf * 2) * 8] = d0;
      *(uint4*)&Wl[o * 32 + swz(o, hf * 2 + 1) * 8] = d1;
      if (SPLIT) {
        uint4 e0, e1;
        e0.x = cvt2lo(v0.x, v0.y, d0.x); e0.y = cvt2lo(v0.z, v0.w, d0.y);
        e0.z = cvt2lo(v1.x, v1.y, d0.z); e0.w = cvt2lo(v1.z, v1.w, d0.w);
        e1.x = cvt2lo(v2.x, v2.y, d1.x); e1.y = cvt2lo(v2.z, v2.w, d1.y);
        e1.z = cvt2lo(v3.x, v3.y, d1.z); e1.w = cvt2lo(v3.z, v3.w, d1.w);
        *(uint4*)&Wl[4096 + o * 32 + swz(o, hf * 2) * 8] = e0;
        *(uint4*)&Wl[4096 + o * 32 + swz(o, hf * 2 + 1) * 8] = e1;
      }
    }
    {
      const int n = tid & 127, ch = (tid >> 7) * 16;
      float val[16];
#pragma unroll
      for (int i = 0; i < 16; ++i) {
        const int cg = cc + ch + i;
        val[i] = tab.p[cg >> 6][tab.bs[cg >> 6] * b + (long long)(cg & 63) * PTS + n0 + n];
      }
      uint4 d0, d1;
      d0.x = cvt2(val[0], val[1]);   d0.y = cvt2(val[2], val[3]);
      d0.z = cvt2(val[4], val[5]);   d0.w = cvt2(val[6], val[7]);
      d1.x = cvt2(val[8], val[9]);   d1.y = cvt2(val[10], val[11]);
      d1.z = cvt2(val[12], val[13]); d1.w = cvt2(val[14], val[15]);
      const int s0 = ch >> 3;
      *(uint4*)&Xl[n * 32 + swz(n, s0) * 8] = d0;
      *(uint4*)&Xl[n * 32 + swz(n, s0 + 1) * 8] = d1;
      if (SPLIT) {
        uint4 e0, e1;
        e0.x = cvt2lo(val[0], val[1], d0.x);   e0.y = cvt2lo(val[2], val[3], d0.y);
        e0.z = cvt2lo(val[4], val[5], d0.z);   e0.w = cvt2lo(val[6], val[7], d0.w);
        e1.x = cvt2lo(val[8], val[9], d1.x);   e1.y = cvt2lo(val[10], val[11], d1.y);
        e1.z = cvt2lo(val[12], val[13], d1.z); e1.w = cvt2lo(val[14], val[15], d1.w);
        *(uint4*)&Xl[4096 + n * 32 + swz(n, s0) * 8] = e0;
        *(uint4*)&Xl[4096 + n * 32 + swz(n, s0 + 1) * 8] = e1;
      }
    }
    __syncthreads();
    bf8 afh[4], bfh[4], afl[4], bfl[4];
#pragma unroll
    for (int mf = 0; mf < 4; ++mf) {
      const int arow = wm * 64 + mf * 16 + (lane & 15);
      const int aoff = arow * 32 + swz(arow, lane >> 4) * 8;
      afh[mf] = *(const bf8*)&Wl[aoff];
      if (SPLIT) afl[mf] = *(const bf8*)&Wl[4096 + aoff];
    }
#pragma unroll
    for (int nf = 0; nf < 4; ++nf) {
      const int brow = wn * 64 + nf * 16 + (lane & 15);
      const int boff = brow * 32 + swz(brow, lane >> 4) * 8;
      bfh[nf] = *(const bf8*)&Xl[boff];
      if (SPLIT) bfl[nf] = *(const bf8*)&Xl[4096 + boff];
    }
#pragma unroll
    for (int mf = 0; mf < 4; ++mf)
#pragma unroll
      for (int nf = 0; nf < 4; ++nf) {
        acc[mf][nf] = __builtin_amdgcn_mfma_f32_16x16x32_bf16(afh[mf], bfh[nf], acc[mf][nf], 0, 0, 0);
        if (SPLIT) {
          acc[mf][nf] = __builtin_amdgcn_mfma_f32_16x16x32_bf16(afl[mf], bfh[nf], acc[mf][nf], 0, 0, 0);
          acc[mf][nf] = __builtin_amdgcn_mfma_f32_16x16x32_bf16(afh[mf], bfl[nf], acc[mf][nf], 0, 0, 0);
        }
      }
  }
  if (MODE == 1) {
#pragma unroll
    for (int mf = 0; mf < 4; ++mf)
#pragma unroll
      for (int r = 0; r < 4; ++r) {
        const int orl = wm * 64 + mf * 16 + (lane >> 4) * 4 + r;
        const int o = o0 + orl;
        const float s = sv[o], bb = bv[o];
        float v = -3.4e38f;
#pragma unroll
        for (int nf = 0; nf < 4; ++nf) v = fmaxf(v, lrelu(fmaf(s, acc[mf][nf][r], bb)));
        v = fmaxf(v, __shfl_xor(v, 1, 64));
        v = fmaxf(v, __shfl_xor(v, 2, 64));
        v = fmaxf(v, __shfl_xor(v, 4, 64));
        v = fmaxf(v, __shfl_xor(v, 8, 64));
        if ((lane & 15) == 0) red[wn][orl] = v;
      }
    __syncthreads();
    if (tid < 128) {
      const float m = fmaxf(red[0][tid], red[1][tid]);
      out[((long long)b * 16 + nt) * 1024 + o0 + tid] = m;
    }
  } else if (MODE == 0) {
#pragma unroll
    for (int mf = 0; mf < 4; ++mf)
#pragma unroll
      for (int r = 0; r < 4; ++r) {
        const int o = o0 + wm * 64 + mf * 16 + (lane >> 4) * 4 + r;
        const float s = sv[o], bb = bv[o];
        const float tv = (tadd != nullptr) ? tadd[(long long)b * O + o] : 0.f;
        float* op = out + ((long long)b * O + o) * PTS + n0 + wn * 64 + (lane & 15);
#pragma unroll
        for (int nf = 0; nf < 4; ++nf)
          op[nf * 16] = lrelu(fmaf(s, acc[mf][nf][r] + tv, bb));
      }
  } else if (MODE == 2) {
#pragma unroll
    for (int mf = 0; mf < 4; ++mf) {
      const int ob = wm * 64 + mf * 16 + (lane >> 4) * 4;
      float s4[4], b4[4];
#pragma unroll
      for (int r = 0; r < 4; ++r) { s4[r] = sv[o0 + ob + r]; b4[r] = bv[o0 + ob + r]; }
#pragma unroll
      for (int nf = 0; nf < 4; ++nf) {
        const int n = n0 + wn * 64 + nf * 16 + (lane & 15);
        float4 v;
        v.x = lrelu(fmaf(s4[0], acc[mf][nf][0], b4[0]));
        v.y = lrelu(fmaf(s4[1], acc[mf][nf][1], b4[1]));
        v.z = lrelu(fmaf(s4[2], acc[mf][nf][2], b4[2]));
        v.w = lrelu(fmaf(s4[3], acc[mf][nf][3], b4[3]));
        *(float4*)&out[((long long)b * PTS + n) * O + o0 + ob] = v;
      }
    }
  } else {  // MODE 3: affine only, f32 [b][PTS][O]
#pragma unroll
    for (int mf = 0; mf < 4; ++mf) {
      const int ob = wm * 64 + mf * 16 + (lane >> 4) * 4;
      float s4[4], b4[4];
#pragma unroll
      for (int r = 0; r < 4; ++r) { s4[r] = sv[o0 + ob + r]; b4[r] = bv[o0 + ob + r]; }
#pragma unroll
      for (int nf = 0; nf < 4; ++nf) {
        const int n = n0 + wn * 64 + nf * 16 + (lane & 15);
        float4 v;
        v.x = fmaf(s4[0], acc[mf][nf][0], b4[0]);
        v.y = fmaf(s4[1], acc[mf][nf][1], b4[1]);
        v.z = fmaf(s4[2], acc[mf][nf][2], b4[2]);
        v.w = fmaf(s4[3], acc[mf][nf][3], b4[3]);
        *(float4*)&out[((long long)b * PTS + n) * O + o0 + ob] = v;
      }
    }
  }
}

// ---------------- finalize global max g[b][1024] ----------------
__global__ __launch_bounds__(256) void gfin_k(const float* __restrict__ gp, float* __restrict__ g) {
  const int i = blockIdx.x * 256 + threadIdx.x;
  const int b = i >> 10, o = i & 1023;
  float m = -3.4e38f;
#pragma unroll 4
  for (int t = 0; t < 16; ++t) m = fmaxf(m, gp[((long long)b * 16 + t) * 1024 + o]);
  g[i] = m;
}

// ---------------- tvec (f32 exact) ----------------
__global__ __launch_bounds__(256) void tvec_k(
    const float* __restrict__ cls, const float* __restrict__ wc, const float* __restrict__ sc,
    const float* __restrict__ bc, const float* __restrict__ g, const float* __restrict__ wf1,
    float* __restrict__ tvec) {
  __shared__ float gs[1024];
  __shared__ float cvs[64];
  const int b = blockIdx.x, tid = threadIdx.x;
  for (int q = tid; q < 1024; q += 256) gs[q] = g[b * 1024 + q];
  if (tid < 64) {
    float a = 0.f;
#pragma unroll
    for (int j = 0; j < 16; ++j) a = fmaf(wc[tid * 16 + j], cls[b * 16 + j], a);
    cvs[tid] = lrelu(fmaf(sc[tid], a, bc[tid]));
  }
  __syncthreads();
  const float* wr = wf1 + (long long)tid * 1280;
  float a0 = 0.f, a1 = 0.f;
  for (int c = 0; c < 1024; c += 4) {
    const float4 w = *(const float4*)&wr[c];
    const float4 gv = *(const float4*)&gs[c];
    a0 = fmaf(w.x, gv.x, a0); a1 = fmaf(w.y, gv.y, a1);
    a0 = fmaf(w.z, gv.z, a0); a1 = fmaf(w.w, gv.w, a1);
  }
#pragma unroll
  for (int c = 0; c < 64; c += 4) {
    const float4 w = *(const float4*)&wr[1024 + c];
    const float4 cv = *(const float4*)&cvs[c];
    a0 = fmaf(w.x, cv.x, a0); a1 = fmaf(w.y, cv.y, a1);
    a0 = fmaf(w.z, cv.z, a0); a1 = fmaf(w.w, cv.w, a1);
  }
  tvec[b * 256 + tid] = a0 + a1;
}

// ---------------- logits + log_softmax ----------------
__global__ __launch_bounds__(256) void logits_k(const float* __restrict__ f3t, const float* __restrict__ wf4,
                                                float* __restrict__ out) {
  __shared__ float wT[6464];
  const int tid = threadIdx.x, lane = tid & 63, wv = tid >> 6;
  for (int q = tid; q < 6400; q += 256) {
    const int o = q >> 7, c = q & 127;
    wT[c * 50 + o] = wf4[q];
  }
  __syncthreads();
  const long long pn = (long long)blockIdx.x * 4 + wv;
  const float lo = f3t[pn * 128 + lane], hi = f3t[pn * 128 + 64 + lane];
  float a0 = 0.f, a1 = 0.f;
#pragma unroll
  for (int c = 0; c < 64; c += 2) {
    a0 = fmaf(wT[c * 50 + lane], rl(lo, c), a0);
    a1 = fmaf(wT[(c + 1) * 50 + lane], rl(lo, c + 1), a1);
  }
#pragma unroll
  for (int c = 0; c < 64; c += 2) {
    a0 = fmaf(wT[(64 + c) * 50 + lane], rl(hi, c), a0);
    a1 = fmaf(wT[(65 + c) * 50 + lane], rl(hi, c + 1), a1);
  }
  const float logit = (lane < 50) ? (a0 + a1) : -3.4e38f;
  float M = logit;
#pragma unroll
  for (int mask = 1; mask < 64; mask <<= 1) M = fmaxf(M, __shfl_xor(M, mask, 64));
  const float ex = (lane < 50) ? __expf(logit - M) : 0.f;
  float S = ex;
#pragma unroll
  for (int mask = 1; mask < 64; mask <<= 1) S += __shfl_xor(S, mask, 64);
  if (lane < 50) out[pn * 50 + lane] = logit - M - __logf(S);
}

extern "C" void kernel_launch(void* const* d_in, const int* in_sizes, int n_in,
                              void* d_out, int out_size, void* d_ws, size_t ws_size,
                              hipStream_t stream) {
  (void)in_sizes; (void)n_in; (void)out_size;
  const float* points = (const float*)d_in[0];
  const float* cls = (const float*)d_in[1];
  const float* w1 = (const float*)d_in[2];
  const float* s1 = (const float*)d_in[3];
  const float* b1 = (const float*)d_in[4];
  const float* w2 = (const float*)d_in[5];
  const float* s2 = (const float*)d_in[6];
  const float* b2 = (const float*)d_in[7];
  const float* w3 = (const float*)d_in[8];
  const float* s3 = (const float*)d_in[9];
  const float* b3 = (const float*)d_in[10];
  const float* w4 = (const float*)d_in[11];
  const float* s4 = (const float*)d_in[12];
  const float* b4 = (const float*)d_in[13];
  const float* w5 = (const float*)d_in[14];
  const float* s5 = (const float*)d_in[15];
  const float* b5 = (const float*)d_in[16];
  const float* w6 = (const float*)d_in[17];
  const float* s6 = (const float*)d_in[18];
  const float* b6 = (const float*)d_in[19];
  const float* wc = (const float*)d_in[20];
  const float* sc = (const float*)d_in[21];
  const float* bc = (const float*)d_in[22];
  const float* wf1 = (const float*)d_in[23];
  const float* sf1 = (const float*)d_in[24];
  const float* bf1 = (const float*)d_in[25];
  const float* wf2 = (const float*)d_in[26];
  const float* sf2 = (const float*)d_in[27];
  const float* bf2 = (const float*)d_in[28];
  const float* wf3 = (const float*)d_in[29];
  const float* sf3 = (const float*)d_in[30];
  const float* bf3 = (const float*)d_in[31];
  const float* wf4 = (const float*)d_in[32];
  float* out = (float*)d_out;
  float* ws = (float*)d_ws;

  // workspace (floats):
  // x1c@0  x2c@2097152  x3c@4194304  f1c@8388608(..16777216)
  // PQf (f32, 4.2M floats) + f3t time-share the f1c region; f2c aliases x*c (dead)
  float* x1c = ws;
  float* x2c = ws + 2097152LL;
  float* x3c = ws + 4194304LL;
  float* f1c = ws + 8388608LL;
  float* f2c = ws;
  float* f3t = ws + 8388608LL;
  float* PQf = ws + 8388608LL;
  int* idx = (int*)(ws + 16777216LL);
  float* xxb = ws + 17432576LL;
  float* gpart = ws + 17465344LL;
  float* g = ws + 17727488LL;
  float* tvec = ws + 17743872LL;
  float* wc3 = ws + 17747968LL;
  float* sc3 = ws + 17756160LL;
  float* bc3 = ws + 17756288LL;
  float* wc5 = ws + 17756416LL;
  float* sc5 = ws + 17764608LL;
  float* bc5 = ws + 17764736LL;
  unsigned short* W2hi = (unsigned short*)(ws + 17764864LL);
  unsigned short* W2lo = (unsigned short*)(ws + 17766912LL);
  unsigned short* W4hi = (unsigned short*)(ws + 17768960LL);
  unsigned short* W4lo = (unsigned short*)(ws + 17771008LL);
  const long long staticEnd = 17773056LL;

  const long long DBATCH = (long long)PTS * PTS;
  int NB; float* Dbuf;
  if (ws_size >= (size_t)(staticEnd + 16 * DBATCH) * 4) { NB = 16; Dbuf = ws + staticEnd; }
  else if (ws_size >= (size_t)(staticEnd + 4 * DBATCH) * 4) { NB = 4; Dbuf = ws + staticEnd; }
  else { NB = 2; Dbuf = ws + 8388608LL; }

  SrcTab tabX{{x1c, x2c, x3c, nullptr}, {64LL * PTS, 64LL * PTS, 64LL * PTS, 0}};
  SrcTab tabX1{{x1c, nullptr, nullptr, nullptr}, {64LL * PTS, 0, 0, 0}};
  SrcTab tabX2{{x2c, nullptr, nullptr, nullptr}, {64LL * PTS, 0, 0, 0}};
  SrcTab tabF1{{f1c, f1c + 64 * PTS, f1c + 128 * PTS, f1c + 192 * PTS},
               {256LL * PTS, 256LL * PTS, 256LL * PTS, 256LL * PTS}};
  SrcTab tabF2{{f2c, f2c + 64 * PTS, f2c + 128 * PTS, f2c + 192 * PTS},
               {256LL * PTS, 256LL * PTS, 256LL * PTS, 256LL * PTS}};

  prep_k<<<64, 256, 0, stream>>>(w3, s3, b3, w5, s5, b5, wc3, sc3, bc3, wc5, sc5, bc5);
  wsplit_k<<<32, 256, 0, stream>>>(w2, w4, W2hi, W2lo, W4hi, W4lo);

  // ---- kNN 1 (f32) + edge1 (split-MFMA) ----
  xnorm_k<3><<<128, 256, 0, stream>>>(points, xxb);
  for (int bo = 0; bo < 16; bo += NB) {
    const int nb = (16 - bo < NB) ? (16 - bo) : NB;
    dist_k<3><<<dim3(16, 16, nb), 256, 0, stream>>>(points, xxb, Dbuf, bo);
    select_k<<<nb * 512, 256, 0, stream>>>(Dbuf, idx, bo);
  }
  pq1_k<<<8192, 256, 0, stream>>>(points, w1, s1, b1, PQf);
  edgemf_k<<<4096, 256, 0, stream>>>(PQf, idx, W2hi, W2lo, s2, b2, x1c);

  // ---- kNN 2 + edge2 (split-MFMA) ----
  xnorm_k<64><<<128, 256, 0, stream>>>(x1c, xxb);
  for (int bo = 0; bo < 16; bo += NB) {
    const int nb = (16 - bo < NB) ? (16 - bo) : NB;
    dist_k<64><<<dim3(16, 16, nb), 256, 0, stream>>>(x1c, xxb, Dbuf, bo);
    select_k<<<nb * 512, 256, 0, stream>>>(Dbuf, idx, bo);
  }
  mfgemm_k<3, 1><<<dim3(16, 1, 16), 256, 0, stream>>>(wc3, 64, 0, tabX1, 64, sc3, bc3, nullptr, PQf, 128);
  edgemf_k<<<4096, 256, 0, stream>>>(PQf, idx, W4hi, W4lo, s4, b4, x2c);

  // ---- kNN 3 + edge3 ----
  xnorm_k<64><<<128, 256, 0, stream>>>(x2c, xxb);
  for (int bo = 0; bo < 16; bo += NB) {
    const int nb = (16 - bo < NB) ? (16 - bo) : NB;
    dist_k<64><<<dim3(16, 16, nb), 256, 0, stream>>>(x2c, xxb, Dbuf, bo);
    select_k<<<nb * 512, 256, 0, stream>>>(Dbuf, idx, bo);
  }
  mfgemm_k<3, 1><<<dim3(16, 1, 16), 256, 0, stream>>>(wc5, 64, 0, tabX2, 64, sc5, bc5, nullptr, PQf, 128);
  edge3f_k<<<1024, 256, 0, stream>>>(PQf, idx, x3c);

  // ---- head (split-MFMA) ----
  mfgemm_k<1, 1><<<dim3(16, 8, 16), 256, 0, stream>>>(w6, 192, 0, tabX, 192, s6, b6, nullptr, gpart, 1024);
  gfin_k<<<64, 256, 0, stream>>>(gpart, g);
  tvec_k<<<16, 256, 0, stream>>>(cls, wc, sc, bc, g, wf1, tvec);
  mfgemm_k<0, 1><<<dim3(16, 2, 16), 256, 0, stream>>>(wf1, 1280, 1088, tabX, 192, sf1, bf1, tvec, f1c, 256);
  mfgemm_k<0, 1><<<dim3(16, 2, 16), 256, 0, stream>>>(wf2, 256, 0, tabF1, 256, sf2, bf2, nullptr, f2c, 256);
  mfgemm_k<2, 1><<<dim3(16, 1, 16), 256, 0, stream>>>(wf3, 256, 0, tabF2, 256, sf3, bf3, nullptr, f3t, 128);
  logits_k<<<8192, 256, 0, stream>>>(f3t, wf4, out);
}